// Round 1
// baseline (6292.473 us; speedup 1.0000x reference)
//
#include <hip/hip_runtime.h>
#include <math.h>

#define BSZ 8
#define SEQL 1024
#define DM 512
#define DI 1024
#define DST 16
#define DTR 32
#define NLAYERS 4
#define ALPHA_C 0.2f
#define LNEPS 1e-5f

// ---------------- input embedding: t[b,l,d] = x[b,:,l] @ W_inp + b_inp ----------------
__global__ __launch_bounds__(256) void embed_kernel(const float* __restrict__ x,
                                                    const float* __restrict__ Wi,
                                                    const float* __restrict__ bi,
                                                    float* __restrict__ t) {
    int idx = blockIdx.x * 256 + threadIdx.x;   // over BSZ*SEQL*DM = 4.19M
    if (idx >= BSZ * SEQL * DM) return;
    int d  = idx & (DM - 1);
    int bl = idx >> 9;            // DM = 512 = 2^9
    int l  = bl & (SEQL - 1);
    int b  = bl >> 10;
    const float* xb = x + (size_t)b * 3 * SEQL;
    float acc = bi[d];
    acc += xb[0 * SEQL + l] * Wi[0 * DM + d];
    acc += xb[1 * SEQL + l] * Wi[1 * DM + d];
    acc += xb[2 * SEQL + l] * Wi[2 * DM + d];
    t[idx] = acc;
}

// ---------------- per-row layernorm over DM=512 ----------------
__global__ __launch_bounds__(256) void ln_kernel(const float* __restrict__ t,
                                                 const float* __restrict__ w,
                                                 const float* __restrict__ b,
                                                 float* __restrict__ xn) {
    int row = blockIdx.x;                 // BSZ*SEQL rows
    int tid = threadIdx.x;
    const float* r = t + (size_t)row * DM;
    float v0 = r[tid], v1 = r[tid + 256];
    __shared__ float sh[256], sh2[256];
    sh[tid]  = v0 + v1;
    sh2[tid] = v0 * v0 + v1 * v1;
    __syncthreads();
    for (int off = 128; off > 0; off >>= 1) {
        if (tid < off) { sh[tid] += sh[tid + off]; sh2[tid] += sh2[tid + off]; }
        __syncthreads();
    }
    float mu  = sh[0]  * (1.f / DM);
    float var = sh2[0] * (1.f / DM) - mu * mu;
    float rs  = rsqrtf(var + LNEPS);
    xn[(size_t)row * DM + tid]       = (v0 - mu) * rs * w[tid]       + b[tid];
    xn[(size_t)row * DM + tid + 256] = (v1 - mu) * rs * w[tid + 256] + b[tid + 256];
}

// ---------------- generic fp32 GEMM: C = A[M,K] @ B[K,N] (+bias) (+=C if RES) ----------------
// 64x64 tile, 256 threads, 4x4 per thread, BK=16. M%64==0, N%64==0, K%16==0 assumed.
template <bool RES>
__global__ __launch_bounds__(256) void gemm_kernel(const float* __restrict__ A,
                                                   const float* __restrict__ Bg,
                                                   const float* __restrict__ bias,
                                                   float* __restrict__ C,
                                                   int M, int N, int K) {
    __shared__ float As[16][64];
    __shared__ float Bs[16][64];
    int tid = threadIdx.x;
    int tn = tid & 15, tm = tid >> 4;
    int bm = blockIdx.x, bn = blockIdx.y;
    const float* Ab = A + (size_t)bm * 64 * K;
    const float* Bb = Bg + (size_t)bn * 64;
    float acc[4][4] = {};
    for (int kk = 0; kk < K; kk += 16) {
#pragma unroll
        for (int i = 0; i < 4; i++) {
            int e = tid + 256 * i;       // 1024 elems of A tile
            int m = e >> 4, k = e & 15;
            As[k][m] = Ab[(size_t)m * K + kk + k];
        }
#pragma unroll
        for (int i = 0; i < 4; i++) {
            int e = tid + 256 * i;       // 1024 elems of B tile
            int k = e >> 6, n = e & 63;
            Bs[k][n] = Bb[(size_t)(kk + k) * N + n];
        }
        __syncthreads();
#pragma unroll
        for (int k = 0; k < 16; k++) {
            float4 a  = *(const float4*)&As[k][tm * 4];
            float4 bv = *(const float4*)&Bs[k][tn * 4];
            float av[4] = {a.x, a.y, a.z, a.w};
            float bw[4] = {bv.x, bv.y, bv.z, bv.w};
#pragma unroll
            for (int i = 0; i < 4; i++)
#pragma unroll
                for (int j = 0; j < 4; j++) acc[i][j] += av[i] * bw[j];
        }
        __syncthreads();
    }
    int m0 = bm * 64 + tm * 4;
    int n0 = bn * 64 + tn * 4;
#pragma unroll
    for (int i = 0; i < 4; i++) {
#pragma unroll
        for (int j = 0; j < 4; j++) {
            float v = acc[i][j];
            if (bias) v += bias[n0 + j];
            size_t off = (size_t)(m0 + i) * N + n0 + j;
            if (RES) v += C[off];
            C[off] = v;
        }
    }
}

// ---------------- causal depthwise conv (D_CONV=4) + SiLU ----------------
__global__ __launch_bounds__(256) void conv_kernel(const float* __restrict__ uz,
                                                   const float* __restrict__ cw,
                                                   const float* __restrict__ cb,
                                                   float* __restrict__ uc) {
    int idx = blockIdx.x * 256 + threadIdx.x;   // BSZ*SEQL*DI
    int e  = idx & (DI - 1);
    int bl = idx >> 10;
    int l  = bl & (SEQL - 1);
    int b  = bl >> 10;
    const float* u = uz + (size_t)b * SEQL * 2048;   // u[b,l,e] = uz[(b*L+l)*2048 + e]
    float acc = cb[e];
#pragma unroll
    for (int k = 0; k < 4; k++) {
        int ll = l - 3 + k;
        float uv = (ll >= 0) ? u[(size_t)ll * 2048 + e] : 0.f;
        acc += uv * cw[e * 4 + k];
    }
    acc = acc / (1.f + expf(-acc));   // silu
    uc[idx] = acc;
}

// ---------------- dt = softplus(dbc[:, :32] @ Wdt + bdt) ----------------
__global__ __launch_bounds__(256) void dt_kernel(const float* __restrict__ dbc,
                                                 const float* __restrict__ Wdt,
                                                 const float* __restrict__ bdt,
                                                 float* __restrict__ dt) {
    int idx = blockIdx.x * 256 + threadIdx.x;   // BSZ*SEQL*DI
    int e  = idx & (DI - 1);
    int bl = idx >> 10;
    const float* dr = dbc + (size_t)bl * 64;
    float acc = bdt[e];
#pragma unroll
    for (int r = 0; r < DTR; r++) acc += dr[r] * Wdt[r * DI + e];
    dt[idx] = (acc > 20.f) ? acc : log1pf(expf(acc));
}

// ---------------- sequential Luenberger scan, 16 lanes per (b,e) ----------------
// Fuses: y = (scan_y + Dv*uc) * silu(z), written in-place into uc.
__global__ __launch_bounds__(256) void scan_kernel(float* __restrict__ uc,
                                                   const float* __restrict__ dt,
                                                   const float* __restrict__ dbc,
                                                   const float* __restrict__ uz,
                                                   const float* __restrict__ Alog,
                                                   const float* __restrict__ Dv) {
    int gtid = blockIdx.x * 256 + threadIdx.x;  // BSZ*DI*16 = 131072
    int n   = gtid & 15;
    int idx = gtid >> 4;
    int e = idx & (DI - 1);
    int b = idx >> 10;
    float An = -expf(Alog[e * DST + n]);
    float dv = Dv[e];
    float h = 0.f;
    const float* dtb  = dt  + (size_t)b * SEQL * DI + e;
    float*       ucb  = uc  + (size_t)b * SEQL * DI + e;
    const float* zb   = uz  + (size_t)b * SEQL * 2048 + 1024 + e;
    const float* dbcb = dbc + (size_t)b * SEQL * 64;
    for (int t = 0; t < SEQL; t++) {
        float dtv = dtb[(size_t)t * DI];
        float uv  = ucb[(size_t)t * DI];
        float Bn  = dbcb[t * 64 + DTR + n];
        float Cn  = dbcb[t * 64 + DTR + DST + n];
        h = expf(dtv * An) * h + (dtv * uv) * Bn;
        float p = h * Cn;
        p += __shfl_xor(p, 1, 16);
        p += __shfl_xor(p, 2, 16);
        p += __shfl_xor(p, 4, 16);
        p += __shfl_xor(p, 8, 16);
        float err = uv - p;
        h += ALPHA_C * err * Cn;
        float q = h * Cn;
        q += __shfl_xor(q, 1, 16);
        q += __shfl_xor(q, 2, 16);
        q += __shfl_xor(q, 4, 16);
        q += __shfl_xor(q, 8, 16);
        if (n == 0) {
            float zv = zb[(size_t)t * 2048];
            float sz = zv / (1.f + expf(-zv));
            ucb[(size_t)t * DI] = (q + dv * uv) * sz;
        }
    }
}

// ---------------- mean-pool partials over L chunks ----------------
__global__ __launch_bounds__(512) void pool_kernel(const float* __restrict__ t,
                                                   float* __restrict__ part) {
    int b = blockIdx.x >> 4;
    int c = blockIdx.x & 15;
    int d = threadIdx.x;
    const float* tb = t + ((size_t)b * SEQL + c * 64) * DM + d;
    float s = 0.f;
    for (int l = 0; l < 64; l++) s += tb[(size_t)l * DM];
    part[(size_t)blockIdx.x * DM + d] = s;
}

// ---------------- final: mean, layernorm, classifier ----------------
__global__ __launch_bounds__(512) void final_kernel(const float* __restrict__ part,
                                                    const float* __restrict__ lw,
                                                    const float* __restrict__ lb,
                                                    const float* __restrict__ Wc,
                                                    const float* __restrict__ bc,
                                                    float* __restrict__ out) {
    int b = blockIdx.x;
    int d = threadIdx.x;
    float v = 0.f;
    for (int c = 0; c < 16; c++) v += part[((size_t)b * 16 + c) * DM + d];
    v *= (1.f / SEQL);
    __shared__ float sh[512], sh2[512], nd[512];
    sh[d] = v; sh2[d] = v * v;
    __syncthreads();
    for (int off = 256; off > 0; off >>= 1) {
        if (d < off) { sh[d] += sh[d + off]; sh2[d] += sh2[d + off]; }
        __syncthreads();
    }
    float mu  = sh[0]  * (1.f / DM);
    float var = sh2[0] * (1.f / DM) - mu * mu;
    float rs  = rsqrtf(var + LNEPS);
    nd[d] = (v - mu) * rs * lw[d] + lb[d];
    __syncthreads();
    if (d < 10) {
        float acc = bc[d];
        for (int k = 0; k < DM; k++) acc += nd[k] * Wc[k * 10 + d];
        out[b * 10 + d] = acc;
    }
}

extern "C" void kernel_launch(void* const* d_in, const int* in_sizes, int n_in,
                              void* d_out, int out_size, void* d_ws, size_t ws_size,
                              hipStream_t stream) {
    const float* x      = (const float*)d_in[0];
    const float* W_inp  = (const float*)d_in[1];
    const float* b_inp  = (const float*)d_in[2];
    const float* W_in   = (const float*)d_in[3];
    const float* b_in   = (const float*)d_in[4];
    const float* conv_w = (const float*)d_in[5];
    const float* conv_b = (const float*)d_in[6];
    const float* W_x    = (const float*)d_in[7];
    const float* W_dt   = (const float*)d_in[8];
    const float* b_dt   = (const float*)d_in[9];
    const float* A_log  = (const float*)d_in[10];
    const float* D_skip = (const float*)d_in[11];
    const float* W_out  = (const float*)d_in[12];
    const float* b_out  = (const float*)d_in[13];
    const float* ln_w   = (const float*)d_in[14];
    const float* ln_b   = (const float*)d_in[15];
    const float* lnf_w  = (const float*)d_in[16];
    const float* lnf_b  = (const float*)d_in[17];
    const float* W_cls  = (const float*)d_in[18];
    const float* b_cls  = (const float*)d_in[19];

    float* ws = (float*)d_ws;
    float* t_buf  = ws;                 ws += (size_t)BSZ * SEQL * DM;    // 4.19M
    float* xn     = ws;                 ws += (size_t)BSZ * SEQL * DM;    // 4.19M
    float* uz     = ws;                 ws += (size_t)BSZ * SEQL * 2048;  // 16.8M
    float* uc     = ws;                 ws += (size_t)BSZ * SEQL * DI;    // 8.39M
    float* dbc    = ws;                 ws += (size_t)BSZ * SEQL * 64;    // 0.52M
    float* dtb    = ws;                 ws += (size_t)BSZ * SEQL * DI;    // 8.39M
    float* part   = ws;                 ws += (size_t)128 * DM;           // 65K

    const int M = BSZ * SEQL;   // 8192

    embed_kernel<<<(M * DM + 255) / 256, 256, 0, stream>>>(x, W_inp, b_inp, t_buf);

    for (int i = 0; i < NLAYERS; i++) {
        ln_kernel<<<M, 256, 0, stream>>>(t_buf, ln_w + i * DM, ln_b + i * DM, xn);
        gemm_kernel<false><<<dim3(M / 64, 2048 / 64), 256, 0, stream>>>(
            xn, W_in + (size_t)i * DM * 2048, b_in + i * 2048, uz, M, 2048, DM);
        conv_kernel<<<(M * DI) / 256, 256, 0, stream>>>(
            uz, conv_w + (size_t)i * DI * 4, conv_b + i * DI, uc);
        gemm_kernel<false><<<dim3(M / 64, 64 / 64), 256, 0, stream>>>(
            uc, W_x + (size_t)i * DI * 64, nullptr, dbc, M, 64, DI);
        dt_kernel<<<(M * DI) / 256, 256, 0, stream>>>(
            dbc, W_dt + (size_t)i * DTR * DI, b_dt + i * DI, dtb);
        scan_kernel<<<(BSZ * DI * 16) / 256, 256, 0, stream>>>(
            uc, dtb, dbc, uz, A_log + (size_t)i * DI * DST, D_skip + i * DI);
        gemm_kernel<true><<<dim3(M / 64, DM / 64), 256, 0, stream>>>(
            uc, W_out + (size_t)i * DI * DM, b_out + i * DM, t_buf, M, DM, DI);
    }

    pool_kernel<<<128, 512, 0, stream>>>(t_buf, part);
    final_kernel<<<8, 512, 0, stream>>>(part, lnf_w, lnf_b, W_cls, b_cls, (float*)d_out);
}

// Round 2
// 3000.308 us; speedup vs baseline: 2.0973x; 2.0973x over previous
//
#include <hip/hip_runtime.h>
#include <math.h>

#define BSZ 8
#define SEQL 1024
#define DM 512
#define DI 1024
#define DST 16
#define DTR 32
#define NLAYERS 4
#define ALPHA_C 0.2f
#define LNEPS 1e-5f

// ---------------- input embedding ----------------
__global__ __launch_bounds__(256) void embed_kernel(const float* __restrict__ x,
                                                    const float* __restrict__ Wi,
                                                    const float* __restrict__ bi,
                                                    float* __restrict__ t) {
    int idx = blockIdx.x * 256 + threadIdx.x;
    if (idx >= BSZ * SEQL * DM) return;
    int d  = idx & (DM - 1);
    int bl = idx >> 9;
    int l  = bl & (SEQL - 1);
    int b  = bl >> 10;
    const float* xb = x + (size_t)b * 3 * SEQL;
    float acc = bi[d];
    acc += xb[0 * SEQL + l] * Wi[0 * DM + d];
    acc += xb[1 * SEQL + l] * Wi[1 * DM + d];
    acc += xb[2 * SEQL + l] * Wi[2 * DM + d];
    t[idx] = acc;
}

// ---------------- per-row layernorm over DM=512 ----------------
__global__ __launch_bounds__(256) void ln_kernel(const float* __restrict__ t,
                                                 const float* __restrict__ w,
                                                 const float* __restrict__ b,
                                                 float* __restrict__ xn) {
    int row = blockIdx.x;
    int tid = threadIdx.x;
    const float* r = t + (size_t)row * DM;
    float v0 = r[tid], v1 = r[tid + 256];
    __shared__ float sh[256], sh2[256];
    sh[tid]  = v0 + v1;
    sh2[tid] = v0 * v0 + v1 * v1;
    __syncthreads();
    for (int off = 128; off > 0; off >>= 1) {
        if (tid < off) { sh[tid] += sh[tid + off]; sh2[tid] += sh2[tid + off]; }
        __syncthreads();
    }
    float mu  = sh[0]  * (1.f / DM);
    float var = sh2[0] * (1.f / DM) - mu * mu;
    float rs  = rsqrtf(var + LNEPS);
    xn[(size_t)row * DM + tid]       = (v0 - mu) * rs * w[tid]       + b[tid];
    xn[(size_t)row * DM + tid + 256] = (v1 - mu) * rs * w[tid + 256] + b[tid + 256];
}

// ---------------- fp32 GEMM 64x64 tile (kept for skinny N=64) ----------------
template <bool RES>
__global__ __launch_bounds__(256) void gemm_kernel(const float* __restrict__ A,
                                                   const float* __restrict__ Bg,
                                                   const float* __restrict__ bias,
                                                   float* __restrict__ C,
                                                   int M, int N, int K) {
    __shared__ float As[16][64];
    __shared__ float Bs[16][64];
    int tid = threadIdx.x;
    int tn = tid & 15, tm = tid >> 4;
    int bm = blockIdx.x, bn = blockIdx.y;
    const float* Ab = A + (size_t)bm * 64 * K;
    const float* Bb = Bg + (size_t)bn * 64;
    float acc[4][4] = {};
    for (int kk = 0; kk < K; kk += 16) {
#pragma unroll
        for (int i = 0; i < 4; i++) {
            int e = tid + 256 * i;
            int m = e >> 4, k = e & 15;
            As[k][m] = Ab[(size_t)m * K + kk + k];
        }
#pragma unroll
        for (int i = 0; i < 4; i++) {
            int e = tid + 256 * i;
            int k = e >> 6, n = e & 63;
            Bs[k][n] = Bb[(size_t)(kk + k) * N + n];
        }
        __syncthreads();
#pragma unroll
        for (int k = 0; k < 16; k++) {
            float4 a  = *(const float4*)&As[k][tm * 4];
            float4 bv = *(const float4*)&Bs[k][tn * 4];
            float av[4] = {a.x, a.y, a.z, a.w};
            float bw[4] = {bv.x, bv.y, bv.z, bv.w};
#pragma unroll
            for (int i = 0; i < 4; i++)
#pragma unroll
                for (int j = 0; j < 4; j++) acc[i][j] += av[i] * bw[j];
        }
        __syncthreads();
    }
    int m0 = bm * 64 + tm * 4;
    int n0 = bn * 64 + tn * 4;
#pragma unroll
    for (int i = 0; i < 4; i++) {
#pragma unroll
        for (int j = 0; j < 4; j++) {
            float v = acc[i][j];
            if (bias) v += bias[n0 + j];
            size_t off = (size_t)(m0 + i) * N + n0 + j;
            if (RES) v += C[off];
            C[off] = v;
        }
    }
}

// ---------------- fp32 GEMM 128x128 tile, 8x8 per thread ----------------
template <bool RES>
__global__ __launch_bounds__(256) void gemm128_kernel(const float* __restrict__ A,
                                                      const float* __restrict__ Bg,
                                                      const float* __restrict__ bias,
                                                      float* __restrict__ C,
                                                      int M, int N, int K) {
    __shared__ float As[16][132];   // +4 pad: conflict-free writes, 16B-aligned rows
    __shared__ float Bs[16][128];
    int tid = threadIdx.x;
    int tx = tid & 15, ty = tid >> 4;
    int bm = blockIdx.x, bn = blockIdx.y;
    const float* Ab = A + (size_t)bm * 128 * K;
    const float* Bb = Bg + (size_t)bn * 128;
    float acc[8][8] = {};
    int la_m = tid >> 4, la_k = tid & 15;     // A-tile load coords
    int lb_n = tid & 127, lb_k = tid >> 7;    // B-tile load coords
    for (int kk = 0; kk < K; kk += 16) {
#pragma unroll
        for (int i = 0; i < 8; i++) {
            int m = la_m + 16 * i;
            As[la_k][m] = Ab[(size_t)m * K + kk + la_k];
        }
#pragma unroll
        for (int i = 0; i < 8; i++) {
            int k = lb_k + 2 * i;
            Bs[k][lb_n] = Bb[(size_t)(kk + k) * N + lb_n];
        }
        __syncthreads();
#pragma unroll
        for (int k = 0; k < 16; k++) {
            float4 a0 = *(const float4*)&As[k][ty * 8];
            float4 a1 = *(const float4*)&As[k][ty * 8 + 4];
            float4 b0 = *(const float4*)&Bs[k][tx * 8];
            float4 b1 = *(const float4*)&Bs[k][tx * 8 + 4];
            float av[8] = {a0.x, a0.y, a0.z, a0.w, a1.x, a1.y, a1.z, a1.w};
            float bw[8] = {b0.x, b0.y, b0.z, b0.w, b1.x, b1.y, b1.z, b1.w};
#pragma unroll
            for (int i = 0; i < 8; i++)
#pragma unroll
                for (int j = 0; j < 8; j++) acc[i][j] += av[i] * bw[j];
        }
        __syncthreads();
    }
    int m0 = bm * 128 + ty * 8;
    int n0 = bn * 128 + tx * 8;
#pragma unroll
    for (int i = 0; i < 8; i++) {
        float* crow = C + (size_t)(m0 + i) * N + n0;
#pragma unroll
        for (int jj = 0; jj < 2; jj++) {
            float4 v = *(float4*)&acc[i][jj * 4];
            if (bias) {
                const float* bp = bias + n0 + jj * 4;
                v.x += bp[0]; v.y += bp[1]; v.z += bp[2]; v.w += bp[3];
            }
            if (RES) {
                float4 c = *(float4*)&crow[jj * 4];
                v.x += c.x; v.y += c.y; v.z += c.z; v.w += c.w;
            }
            *(float4*)&crow[jj * 4] = v;
        }
    }
}

// ---------------- causal depthwise conv (D_CONV=4) + SiLU ----------------
__global__ __launch_bounds__(256) void conv_kernel(const float* __restrict__ uz,
                                                   const float* __restrict__ cw,
                                                   const float* __restrict__ cb,
                                                   float* __restrict__ uc) {
    int idx = blockIdx.x * 256 + threadIdx.x;
    int e  = idx & (DI - 1);
    int bl = idx >> 10;
    int l  = bl & (SEQL - 1);
    int b  = bl >> 10;
    const float* u = uz + (size_t)b * SEQL * 2048;
    float acc = cb[e];
#pragma unroll
    for (int k = 0; k < 4; k++) {
        int ll = l - 3 + k;
        float uv = (ll >= 0) ? u[(size_t)ll * 2048 + e] : 0.f;
        acc += uv * cw[e * 4 + k];
    }
    acc = acc / (1.f + expf(-acc));
    uc[idx] = acc;
}

// ---------------- dt = softplus(dbc[:, :32] @ Wdt + bdt) ----------------
__global__ __launch_bounds__(256) void dt_kernel(const float* __restrict__ dbc,
                                                 const float* __restrict__ Wdt,
                                                 const float* __restrict__ bdt,
                                                 float* __restrict__ dt) {
    int idx = blockIdx.x * 256 + threadIdx.x;
    int e  = idx & (DI - 1);
    int bl = idx >> 10;
    const float* dr = dbc + (size_t)bl * 64;
    float acc = bdt[e];
#pragma unroll
    for (int r = 0; r < DTR; r++) acc += dr[r] * Wdt[r * DI + e];
    dt[idx] = (acc > 20.f) ? acc : log1pf(expf(acc));
}

// ---------------- DPP row_ror sum over 16 lanes (rows of 16 == n-groups) ----------------
__device__ __forceinline__ float sum16(float x) {
    x += __int_as_float(__builtin_amdgcn_update_dpp(0, __float_as_int(x), 0x121, 0xf, 0xf, true)); // ror:1
    x += __int_as_float(__builtin_amdgcn_update_dpp(0, __float_as_int(x), 0x122, 0xf, 0xf, true)); // ror:2
    x += __int_as_float(__builtin_amdgcn_update_dpp(0, __float_as_int(x), 0x124, 0xf, 0xf, true)); // ror:4
    x += __int_as_float(__builtin_amdgcn_update_dpp(0, __float_as_int(x), 0x128, 0xf, 0xf, true)); // ror:8
    return x;
}

// ---------------- sequential Luenberger scan v2 ----------------
// 16 lanes per (b,e). Critical chain per t: fma -> mul -> 4x(dpp+add) -> fma.
// Second reduction eliminated via y = p + alpha*(u-p)*sum(C^2).
// Loads double-buffered 8 steps ahead in registers.
#define PF 8
struct Slot { float dt, u, Bv, Cv, z; };

__device__ __forceinline__ void load_chunk(Slot s[PF],
                                           const float* __restrict__ dtp,
                                           const float* __restrict__ ucp,
                                           const float* __restrict__ Bp,
                                           const float* __restrict__ Cp,
                                           const float* __restrict__ zp,
                                           int tc) {
#pragma unroll
    for (int j = 0; j < PF; j++) {
        s[j].dt = dtp[(size_t)(tc + j) * DI];
        s[j].u  = ucp[(size_t)(tc + j) * DI];
        s[j].Bv = Bp[(tc + j) * 64];
        s[j].Cv = Cp[(tc + j) * 64];
        s[j].z  = zp[(size_t)(tc + j) * 2048];
    }
}

__global__ __launch_bounds__(256) void scan_kernel(float* __restrict__ uc,
                                                   const float* __restrict__ dt,
                                                   const float* __restrict__ dbc,
                                                   const float* __restrict__ uz,
                                                   const float* __restrict__ Alog,
                                                   const float* __restrict__ Dv) {
    int gtid = blockIdx.x * 256 + threadIdx.x;  // BSZ*DI*16 = 131072
    int n   = gtid & 15;
    int idx = gtid >> 4;
    int e = idx & (DI - 1);
    int b = idx >> 10;
    float An = -__expf(Alog[e * DST + n]);
    float dv = Dv[e];
    float h = 0.f;
    const float* dtp = dt  + (size_t)b * SEQL * DI + e;
    float*       ucp = uc  + (size_t)b * SEQL * DI + e;
    const float* zp  = uz  + (size_t)b * SEQL * 2048 + 1024 + e;
    const float* Bp  = dbc + (size_t)b * SEQL * 64 + DTR + n;
    const float* Cp  = dbc + (size_t)b * SEQL * 64 + DTR + DST + n;

    Slot s0[PF], s1[PF];
    load_chunk(s0, dtp, ucp, Bp, Cp, zp, 0);

#define PROCESS(S, TC)                                                          \
    {                                                                           \
        _Pragma("unroll")                                                       \
        for (int j = 0; j < PF; j++) {                                          \
            float dtv = S[j].dt, uv = S[j].u, Bn = S[j].Bv, Cn = S[j].Cv;       \
            float Ssq = sum16(Cn * Cn);            /* off-chain */              \
            float a = __expf(dtv * An);                                         \
            float w = (dtv * uv) * Bn;                                          \
            h = fmaf(a, h, w);                                                  \
            float p = sum16(h * Cn);                                            \
            float es = ALPHA_C * (uv - p);                                      \
            h = fmaf(es, Cn, h);                                                \
            if (n == 0) {                                                       \
                float y = p + es * Ssq;                                         \
                float zv = S[j].z;                                              \
                float sz = zv / (1.f + __expf(-zv));                            \
                ucp[(size_t)((TC) + j) * DI] = (y + dv * uv) * sz;              \
            }                                                                   \
        }                                                                       \
    }

    for (int tc = 0; tc < SEQL; tc += 2 * PF) {
        load_chunk(s1, dtp, ucp, Bp, Cp, zp, tc + PF);
        PROCESS(s0, tc);
        if (tc + 2 * PF < SEQL) load_chunk(s0, dtp, ucp, Bp, Cp, zp, tc + 2 * PF);
        PROCESS(s1, tc + PF);
    }
#undef PROCESS
}

// ---------------- mean-pool partials ----------------
__global__ __launch_bounds__(512) void pool_kernel(const float* __restrict__ t,
                                                   float* __restrict__ part) {
    int b = blockIdx.x >> 4;
    int c = blockIdx.x & 15;
    int d = threadIdx.x;
    const float* tb = t + ((size_t)b * SEQL + c * 64) * DM + d;
    float s = 0.f;
    for (int l = 0; l < 64; l++) s += tb[(size_t)l * DM];
    part[(size_t)blockIdx.x * DM + d] = s;
}

// ---------------- final: mean, layernorm, classifier ----------------
__global__ __launch_bounds__(512) void final_kernel(const float* __restrict__ part,
                                                    const float* __restrict__ lw,
                                                    const float* __restrict__ lb,
                                                    const float* __restrict__ Wc,
                                                    const float* __restrict__ bc,
                                                    float* __restrict__ out) {
    int b = blockIdx.x;
    int d = threadIdx.x;
    float v = 0.f;
    for (int c = 0; c < 16; c++) v += part[((size_t)b * 16 + c) * DM + d];
    v *= (1.f / SEQL);
    __shared__ float sh[512], sh2[512], nd[512];
    sh[d] = v; sh2[d] = v * v;
    __syncthreads();
    for (int off = 256; off > 0; off >>= 1) {
        if (d < off) { sh[d] += sh[d + off]; sh2[d] += sh2[d + off]; }
        __syncthreads();
    }
    float mu  = sh[0]  * (1.f / DM);
    float var = sh2[0] * (1.f / DM) - mu * mu;
    float rs  = rsqrtf(var + LNEPS);
    nd[d] = (v - mu) * rs * lw[d] + lb[d];
    __syncthreads();
    if (d < 10) {
        float acc = bc[d];
        for (int k = 0; k < DM; k++) acc += nd[k] * Wc[k * 10 + d];
        out[b * 10 + d] = acc;
    }
}

extern "C" void kernel_launch(void* const* d_in, const int* in_sizes, int n_in,
                              void* d_out, int out_size, void* d_ws, size_t ws_size,
                              hipStream_t stream) {
    const float* x      = (const float*)d_in[0];
    const float* W_inp  = (const float*)d_in[1];
    const float* b_inp  = (const float*)d_in[2];
    const float* W_in   = (const float*)d_in[3];
    const float* b_in   = (const float*)d_in[4];
    const float* conv_w = (const float*)d_in[5];
    const float* conv_b = (const float*)d_in[6];
    const float* W_x    = (const float*)d_in[7];
    const float* W_dt   = (const float*)d_in[8];
    const float* b_dt   = (const float*)d_in[9];
    const float* A_log  = (const float*)d_in[10];
    const float* D_skip = (const float*)d_in[11];
    const float* W_out  = (const float*)d_in[12];
    const float* b_out  = (const float*)d_in[13];
    const float* ln_w   = (const float*)d_in[14];
    const float* ln_b   = (const float*)d_in[15];
    const float* lnf_w  = (const float*)d_in[16];
    const float* lnf_b  = (const float*)d_in[17];
    const float* W_cls  = (const float*)d_in[18];
    const float* b_cls  = (const float*)d_in[19];

    float* ws = (float*)d_ws;
    float* t_buf  = ws;                 ws += (size_t)BSZ * SEQL * DM;
    float* xn     = ws;                 ws += (size_t)BSZ * SEQL * DM;
    float* uz     = ws;                 ws += (size_t)BSZ * SEQL * 2048;
    float* uc     = ws;                 ws += (size_t)BSZ * SEQL * DI;
    float* dbc    = ws;                 ws += (size_t)BSZ * SEQL * 64;
    float* dtb    = ws;                 ws += (size_t)BSZ * SEQL * DI;
    float* part   = ws;                 ws += (size_t)128 * DM;

    const int M = BSZ * SEQL;   // 8192

    embed_kernel<<<(M * DM + 255) / 256, 256, 0, stream>>>(x, W_inp, b_inp, t_buf);

    for (int i = 0; i < NLAYERS; i++) {
        ln_kernel<<<M, 256, 0, stream>>>(t_buf, ln_w + i * DM, ln_b + i * DM, xn);
        gemm128_kernel<false><<<dim3(M / 128, 2048 / 128), 256, 0, stream>>>(
            xn, W_in + (size_t)i * DM * 2048, b_in + i * 2048, uz, M, 2048, DM);
        conv_kernel<<<(M * DI) / 256, 256, 0, stream>>>(
            uz, conv_w + (size_t)i * DI * 4, conv_b + i * DI, uc);
        gemm_kernel<false><<<dim3(M / 64, 1), 256, 0, stream>>>(
            uc, W_x + (size_t)i * DI * 64, nullptr, dbc, M, 64, DI);
        dt_kernel<<<(M * DI) / 256, 256, 0, stream>>>(
            dbc, W_dt + (size_t)i * DTR * DI, b_dt + i * DI, dtb);
        scan_kernel<<<(BSZ * DI * 16) / 256, 256, 0, stream>>>(
            uc, dtb, dbc, uz, A_log + (size_t)i * DI * DST, D_skip + i * DI);
        gemm128_kernel<true><<<dim3(M / 128, DM / 128), 256, 0, stream>>>(
            uc, W_out + (size_t)i * DI * DM, b_out + i * DM, t_buf, M, DM, DI);
    }

    pool_kernel<<<128, 512, 0, stream>>>(t_buf, part);
    final_kernel<<<8, 512, 0, stream>>>(part, lnf_w, lnf_b, W_cls, b_cls, (float*)d_out);
}

// Round 3
// 1740.370 us; speedup vs baseline: 3.6156x; 1.7239x over previous
//
#include <hip/hip_runtime.h>
#include <hip/hip_bf16.h>
#include <math.h>

#define BSZ 8
#define SEQL 1024
#define DM 512
#define DI 1024
#define DST 16
#define DTR 32
#define NLAYERS 4
#define ALPHA_C 0.2f
#define LNEPS 1e-5f
#define CH 32          // scan LDS chunk length (t-steps)
#define KSPLIT 4       // split-K factor for the skinny N=64 GEMM

typedef __attribute__((ext_vector_type(8))) short short8;
typedef __attribute__((ext_vector_type(4))) float f32x4;

// async global->LDS, 16B per lane. LDS dest = wave-uniform base + lane*16.
__device__ __forceinline__ void gll16(const void* g, void* l) {
    __builtin_amdgcn_global_load_lds(
        (const __attribute__((address_space(1))) unsigned int*)g,
        (__attribute__((address_space(3))) unsigned int*)l, 16, 0, 0);
}

// DPP row_ror sum over rows of 16 lanes (rows align with our n-groups)
__device__ __forceinline__ float sum16(float x) {
    x += __int_as_float(__builtin_amdgcn_update_dpp(0, __float_as_int(x), 0x121, 0xf, 0xf, true));
    x += __int_as_float(__builtin_amdgcn_update_dpp(0, __float_as_int(x), 0x122, 0xf, 0xf, true));
    x += __int_as_float(__builtin_amdgcn_update_dpp(0, __float_as_int(x), 0x124, 0xf, 0xf, true));
    x += __int_as_float(__builtin_amdgcn_update_dpp(0, __float_as_int(x), 0x128, 0xf, 0xf, true));
    return x;
}

// ---------------- input embedding ----------------
__global__ __launch_bounds__(256) void embed_kernel(const float* __restrict__ x,
                                                    const float* __restrict__ Wi,
                                                    const float* __restrict__ bi,
                                                    float* __restrict__ t) {
    int idx = blockIdx.x * 256 + threadIdx.x;
    if (idx >= BSZ * SEQL * DM) return;
    int d  = idx & (DM - 1);
    int bl = idx >> 9;
    int l  = bl & (SEQL - 1);
    int b  = bl >> 10;
    const float* xb = x + (size_t)b * 3 * SEQL;
    float acc = bi[d];
    acc += xb[0 * SEQL + l] * Wi[0 * DM + d];
    acc += xb[1 * SEQL + l] * Wi[1 * DM + d];
    acc += xb[2 * SEQL + l] * Wi[2 * DM + d];
    t[idx] = acc;
}

// ---------------- layernorm over DM=512, writes bf16 ----------------
__global__ __launch_bounds__(256) void ln_kernel(const float* __restrict__ t,
                                                 const float* __restrict__ w,
                                                 const float* __restrict__ b,
                                                 __hip_bfloat16* __restrict__ xn) {
    int row = blockIdx.x;
    int tid = threadIdx.x;
    const float* r = t + (size_t)row * DM;
    float v0 = r[tid], v1 = r[tid + 256];
    __shared__ float sh[256], sh2[256];
    sh[tid]  = v0 + v1;
    sh2[tid] = v0 * v0 + v1 * v1;
    __syncthreads();
    for (int off = 128; off > 0; off >>= 1) {
        if (tid < off) { sh[tid] += sh[tid + off]; sh2[tid] += sh2[tid + off]; }
        __syncthreads();
    }
    float mu  = sh[0]  * (1.f / DM);
    float var = sh2[0] * (1.f / DM) - mu * mu;
    float rs  = rsqrtf(var + LNEPS);
    xn[(size_t)row * DM + tid]       = __float2bfloat16((v0 - mu) * rs * w[tid]       + b[tid]);
    xn[(size_t)row * DM + tid + 256] = __float2bfloat16((v1 - mu) * rs * w[tid + 256] + b[tid + 256]);
}

// ---------------- transpose + fp32->bf16: W[K][N] -> Wt[N][K], per layer (grid.z) ----------------
__global__ __launch_bounds__(256) void transpose_bf_kernel(const float* __restrict__ W,
                                                           __hip_bfloat16* __restrict__ Wt,
                                                           int K, int N, size_t lstride) {
    const float* Wl = W + (size_t)blockIdx.z * lstride;
    __hip_bfloat16* Wtl = Wt + (size_t)blockIdx.z * lstride;
    __shared__ float tile[32][33];
    int kk = blockIdx.x * 32, nn = blockIdx.y * 32;
    int tx = threadIdx.x & 31, ty = threadIdx.x >> 5;
#pragma unroll
    for (int i = 0; i < 32; i += 8)
        tile[ty + i][tx] = Wl[(size_t)(kk + ty + i) * N + nn + tx];
    __syncthreads();
#pragma unroll
    for (int i = 0; i < 32; i += 8)
        Wtl[(size_t)(nn + ty + i) * K + kk + tx] = __float2bfloat16(tile[tx][ty + i]);
}

// ---------------- bf16 MFMA GEMM: C = A[M,K] @ Bt[N,K]^T + bias (+=C if RES) ----------------
// 128x128 tile, BK=32, 4 waves (2x2 of 64x64), 16x16x32 MFMA.
// LDS rows of 64B, 16B chunks XOR-swizzled by (row>>1)&3 -> 2-way (free) bank access.
template <bool RES>
__global__ __launch_bounds__(256) void gemm_mfma_kernel(const short* __restrict__ A,
                                                        const short* __restrict__ Bt,
                                                        const float* __restrict__ bias,
                                                        float* __restrict__ C,
                                                        int M, int N, int K) {
    __shared__ __align__(16) short As[128 * 32];
    __shared__ __align__(16) short Bs[128 * 32];
    int tid = threadIdx.x;
    int w = tid >> 6, lane = tid & 63;
    int quad = lane >> 4, ml = lane & 15;
    int wm = w & 1, wn = w >> 1;
    const short* Ab = A + (size_t)blockIdx.x * 128 * K;
    const short* Bb = Bt + (size_t)blockIdx.y * 128 * K;
    f32x4 acc[4][4] = {};
    // staging slots: s = i*256 + tid ; row = s>>2 ; phys chunk = s&3 ; logical = phys ^ ((row>>1)&3)
    int s0 = tid, s1 = tid + 256;
    int r0 = s0 >> 2, c0 = (s0 & 3) ^ ((r0 >> 1) & 3);
    int r1 = s1 >> 2, c1 = (s1 & 3) ^ ((r1 >> 1) & 3);
    // fragment LDS offsets (shorts)
    int aoff[4], boff[4];
#pragma unroll
    for (int t = 0; t < 4; t++) {
        int ra = wm * 64 + t * 16 + ml;
        aoff[t] = ra * 32 + (quad ^ ((ra >> 1) & 3)) * 8;
        int rb = wn * 64 + t * 16 + ml;
        boff[t] = rb * 32 + (quad ^ ((rb >> 1) & 3)) * 8;
    }
    for (int kk = 0; kk < K; kk += 32) {
        gll16(Ab + (size_t)r0 * K + kk + c0 * 8, As + (size_t)(w * 64) * 8);
        gll16(Ab + (size_t)r1 * K + kk + c1 * 8, As + (size_t)(256 + w * 64) * 8);
        gll16(Bb + (size_t)r0 * K + kk + c0 * 8, Bs + (size_t)(w * 64) * 8);
        gll16(Bb + (size_t)r1 * K + kk + c1 * 8, Bs + (size_t)(256 + w * 64) * 8);
        __syncthreads();   // drain vmcnt: LDS tiles ready
        short8 af[4], bfr[4];
#pragma unroll
        for (int t = 0; t < 4; t++) af[t]  = *(const short8*)&As[aoff[t]];
#pragma unroll
        for (int t = 0; t < 4; t++) bfr[t] = *(const short8*)&Bs[boff[t]];
#pragma unroll
        for (int mt = 0; mt < 4; mt++)
#pragma unroll
            for (int nt = 0; nt < 4; nt++)
                acc[mt][nt] = __builtin_amdgcn_mfma_f32_16x16x32_bf16(af[mt], bfr[nt], acc[mt][nt], 0, 0, 0);
        __syncthreads();   // reads done before next stage overwrites
    }
#pragma unroll
    for (int mt = 0; mt < 4; mt++) {
#pragma unroll
        for (int nt = 0; nt < 4; nt++) {
            int n = blockIdx.y * 128 + wn * 64 + nt * 16 + ml;
            float bv = bias[n];
#pragma unroll
            for (int r = 0; r < 4; r++) {
                int m = blockIdx.x * 128 + wm * 64 + mt * 16 + quad * 4 + r;
                size_t off = (size_t)m * N + n;
                float v = acc[mt][nt][r] + bv;
                if (RES) v += C[off];
                C[off] = v;
            }
        }
    }
}

// ---------------- causal depthwise conv (D_CONV=4) + SiLU ----------------
__global__ __launch_bounds__(256) void conv_kernel(const float* __restrict__ uz,
                                                   const float* __restrict__ cw,
                                                   const float* __restrict__ cb,
                                                   float* __restrict__ uc) {
    int idx = blockIdx.x * 256 + threadIdx.x;
    int e  = idx & (DI - 1);
    int bl = idx >> 10;
    int l  = bl & (SEQL - 1);
    int b  = bl >> 10;
    const float* u = uz + (size_t)b * SEQL * 2048;
    float acc = cb[e];
#pragma unroll
    for (int k = 0; k < 4; k++) {
        int ll = l - 3 + k;
        float uv = (ll >= 0) ? u[(size_t)ll * 2048 + e] : 0.f;
        acc += uv * cw[e * 4 + k];
    }
    acc = acc / (1.f + expf(-acc));
    uc[idx] = acc;
}

// ---------------- fp32 GEMM 64-wide, split-K: part[ks][M][64] ----------------
__global__ __launch_bounds__(256) void gemm64_splitk_kernel(const float* __restrict__ A,
                                                            const float* __restrict__ Bg,
                                                            float* __restrict__ part,
                                                            int M, int K) {
    __shared__ float As[16][64];
    __shared__ float Bs[16][64];
    const int N = 64;
    int tid = threadIdx.x;
    int tn = tid & 15, tm = tid >> 4;
    int bm = blockIdx.x, ks = blockIdx.y;
    int k0 = ks * (K / KSPLIT), k1 = k0 + K / KSPLIT;
    const float* Ab = A + (size_t)bm * 64 * K;
    float acc[4][4] = {};
    for (int kk = k0; kk < k1; kk += 16) {
#pragma unroll
        for (int i = 0; i < 4; i++) {
            int e = tid + 256 * i;
            int m = e >> 4, k = e & 15;
            As[k][m] = Ab[(size_t)m * K + kk + k];
        }
#pragma unroll
        for (int i = 0; i < 4; i++) {
            int e = tid + 256 * i;
            int k = e >> 6, n = e & 63;
            Bs[k][n] = Bg[(size_t)(kk + k) * N + n];
        }
        __syncthreads();
#pragma unroll
        for (int k = 0; k < 16; k++) {
            float4 a  = *(const float4*)&As[k][tm * 4];
            float4 bv = *(const float4*)&Bs[k][tn * 4];
            float av[4] = {a.x, a.y, a.z, a.w};
            float bw[4] = {bv.x, bv.y, bv.z, bv.w};
#pragma unroll
            for (int i = 0; i < 4; i++)
#pragma unroll
                for (int j = 0; j < 4; j++) acc[i][j] += av[i] * bw[j];
        }
        __syncthreads();
    }
    int m0 = bm * 64 + tm * 4;
    int n0 = tn * 4;
#pragma unroll
    for (int i = 0; i < 4; i++)
#pragma unroll
        for (int j = 0; j < 4; j++)
            part[((size_t)ks * M + m0 + i) * 64 + n0 + j] = acc[i][j];
}

// ---------------- reduce split-K partials; emit dtc[M][32], BC[M][32] interleaved, ssq[M] ----------------
__global__ __launch_bounds__(256) void repack_kernel(const float* __restrict__ part,
                                                     float* __restrict__ dtc,
                                                     float* __restrict__ bc,
                                                     float* __restrict__ ssqb,
                                                     int M) {
    int m = blockIdx.x * 4 + (threadIdx.x >> 6);
    int j = threadIdx.x & 63;
    float v = 0.f;
#pragma unroll
    for (int ks = 0; ks < KSPLIT; ks++) v += part[((size_t)ks * M + m) * 64 + j];
    float s = sum16(v * v);        // row 3 (lanes 48..63) = sum of C^2
    if (j < 32) dtc[(size_t)m * 32 + j] = v;
    else if (j < 48) bc[(size_t)m * 32 + 2 * (j - 32)] = v;          // B_n -> even
    else {
        bc[(size_t)m * 32 + 2 * (j - 48) + 1] = v;                    // C_n -> odd
        if (j == 48) ssqb[m] = s;
    }
}

// ---------------- dt = softplus(dtc @ Wdt + bdt), written into u-half of uz ----------------
__global__ __launch_bounds__(256) void dt_kernel(const float* __restrict__ dtc,
                                                 const float* __restrict__ Wdt,
                                                 const float* __restrict__ bdt,
                                                 float* __restrict__ uzdt) {
    int idx = blockIdx.x * 256 + threadIdx.x;
    int e  = idx & (DI - 1);
    int bl = idx >> 10;
    const float* dr = dtc + (size_t)bl * 32;
    float acc = bdt[e];
#pragma unroll
    for (int r = 0; r < DTR; r++) acc += dr[r] * Wdt[r * DI + e];
    uzdt[(size_t)bl * 2048 + e] = (acc > 20.f) ? acc : log1pf(expf(acc));
}

// ---------------- scan v4: LDS-chunked, double-buffered async staging ----------------
__device__ __forceinline__ void scan_stage(float* sBC, float* sDT, float* sU, float* sZ, float* sSQ,
                                           const float* __restrict__ ucb,
                                           const float* __restrict__ uzb,
                                           const float* __restrict__ bcb,
                                           const float* __restrict__ sqb,
                                           int e_base, int tid, int tc) {
    int w = tid >> 6, lane = tid & 63;
    // BC: 32t x 16n x 2 = 4KB, all 256 threads, 16B each
    gll16(bcb + (size_t)(tc + (tid >> 3)) * 32 + (tid & 7) * 4, sBC + (size_t)w * 256);
    if (w < 2) {
        int i = tid;   // 0..127
        const float* gdt = uzb + (size_t)(tc + (i >> 2)) * 2048 + e_base + (i & 3) * 4;
        gll16(gdt, sDT + (size_t)w * 256);
        const float* gz = uzb + (size_t)(tc + (i >> 2)) * 2048 + 1024 + e_base + (i & 3) * 4;
        gll16(gz, sZ + (size_t)w * 256);
    } else {
        int i = tid - 128;
        const float* gu = ucb + (size_t)(tc + (i >> 2)) * 1024 + e_base + (i & 3) * 4;
        gll16(gu, sU + (size_t)(w - 2) * 256);
        if (w == 2 && lane < 8)
            gll16(sqb + tc + lane * 4, sSQ);
    }
}

__global__ __launch_bounds__(256) void scan_kernel(const float* __restrict__ uc,
                                                   const float* __restrict__ uz,     // dt in u-half, z in z-half
                                                   const float* __restrict__ bcb,
                                                   const float* __restrict__ ssqb,
                                                   const float* __restrict__ Alog,
                                                   const float* __restrict__ Dv,
                                                   __hip_bfloat16* __restrict__ out) {
    __shared__ __align__(16) float sBC[2][CH * 32];
    __shared__ __align__(16) float sDT[2][CH * 16];
    __shared__ __align__(16) float sU [2][CH * 16];
    __shared__ __align__(16) float sZ [2][CH * 16];
    __shared__ __align__(16) float sSQ[2][CH];
    int tid = threadIdx.x;
    int g = tid >> 4, n = tid & 15;
    int b = blockIdx.x >> 6;
    int e_base = (blockIdx.x & 63) << 4;
    int e = e_base + g;
    float An = -__expf(Alog[e * DST + n]);
    float dv = Dv[e];
    const float* ucb = uc + (size_t)b * SEQL * DI;
    const float* uzb = uz + (size_t)b * SEQL * 2048;
    const float* bcp = bcb + (size_t)b * SEQL * 32;
    const float* sqb = ssqb + (size_t)b * SEQL;
    __hip_bfloat16* ob = out + (size_t)b * SEQL * DI + e;
    float h = 0.f;
    scan_stage(sBC[0], sDT[0], sU[0], sZ[0], sSQ[0], ucb, uzb, bcp, sqb, e_base, tid, 0);
    int buf = 0;
    for (int tc = 0; tc < SEQL; tc += CH) {
        __syncthreads();   // drains current buf's async loads
        if (tc + CH < SEQL)
            scan_stage(sBC[buf ^ 1], sDT[buf ^ 1], sU[buf ^ 1], sZ[buf ^ 1], sSQ[buf ^ 1],
                       ucb, uzb, bcp, sqb, e_base, tid, tc + CH);
        const float* pBC = sBC[buf];
        const float* pDT = sDT[buf];
        const float* pU  = sU[buf];
        const float* pZ  = sZ[buf];
        const float* pSQ = sSQ[buf];
#pragma unroll 8
        for (int t = 0; t < CH; t++) {
            float2 bcv = *(const float2*)&pBC[t * 32 + n * 2];   // (B_n, C_n)
            float dtv = pDT[t * 16 + g];
            float uv  = pU[t * 16 + g];
            float a = __expf(dtv * An);
            h = fmaf(a, h, dtv * uv * bcv.x);
            float p = sum16(h * bcv.y);
            float es = uv - p;
            h = fmaf(ALPHA_C * es, bcv.y, h);
            if (n == 0) {
                float sq = pSQ[t];
                float zv = pZ[t * 16 + g];
                float y = fmaf(ALPHA_C * es, sq, p) + dv * uv;   // <h',C> + D*u
                float sz = zv / (1.f + __expf(-zv));
                ob[(size_t)(tc + t) * DI] = __float2bfloat16(y * sz);
            }
        }
        buf ^= 1;
    }
}

// ---------------- mean-pool partials ----------------
__global__ __launch_bounds__(512) void pool_kernel(const float* __restrict__ t,
                                                   float* __restrict__ part) {
    int b = blockIdx.x >> 4;
    int c = blockIdx.x & 15;
    int d = threadIdx.x;
    const float* tb = t + ((size_t)b * SEQL + c * 64) * DM + d;
    float s = 0.f;
    for (int l = 0; l < 64; l++) s += tb[(size_t)l * DM];
    part[(size_t)blockIdx.x * DM + d] = s;
}

// ---------------- final: mean, layernorm, classifier ----------------
__global__ __launch_bounds__(512) void final_kernel(const float* __restrict__ part,
                                                    const float* __restrict__ lw,
                                                    const float* __restrict__ lb,
                                                    const float* __restrict__ Wc,
                                                    const float* __restrict__ bc,
                                                    float* __restrict__ out) {
    int b = blockIdx.x;
    int d = threadIdx.x;
    float v = 0.f;
    for (int c = 0; c < 16; c++) v += part[((size_t)b * 16 + c) * DM + d];
    v *= (1.f / SEQL);
    __shared__ float sh[512], sh2[512], nd[512];
    sh[d] = v; sh2[d] = v * v;
    __syncthreads();
    for (int off = 256; off > 0; off >>= 1) {
        if (d < off) { sh[d] += sh[d + off]; sh2[d] += sh2[d + off]; }
        __syncthreads();
    }
    float mu  = sh[0]  * (1.f / DM);
    float var = sh2[0] * (1.f / DM) - mu * mu;
    float rs  = rsqrtf(var + LNEPS);
    nd[d] = (v - mu) * rs * lw[d] + lb[d];
    __syncthreads();
    if (d < 10) {
        float acc = bc[d];
        for (int k = 0; k < DM; k++) acc += nd[k] * Wc[k * 10 + d];
        out[b * 10 + d] = acc;
    }
}

extern "C" void kernel_launch(void* const* d_in, const int* in_sizes, int n_in,
                              void* d_out, int out_size, void* d_ws, size_t ws_size,
                              hipStream_t stream) {
    const float* x      = (const float*)d_in[0];
    const float* W_inp  = (const float*)d_in[1];
    const float* b_inp  = (const float*)d_in[2];
    const float* W_in   = (const float*)d_in[3];
    const float* b_in   = (const float*)d_in[4];
    const float* conv_w = (const float*)d_in[5];
    const float* conv_b = (const float*)d_in[6];
    const float* W_x    = (const float*)d_in[7];
    const float* W_dt   = (const float*)d_in[8];
    const float* b_dt   = (const float*)d_in[9];
    const float* A_log  = (const float*)d_in[10];
    const float* D_skip = (const float*)d_in[11];
    const float* W_out  = (const float*)d_in[12];
    const float* b_out  = (const float*)d_in[13];
    const float* ln_w   = (const float*)d_in[14];
    const float* ln_b   = (const float*)d_in[15];
    const float* lnf_w  = (const float*)d_in[16];
    const float* lnf_b  = (const float*)d_in[17];
    const float* W_cls  = (const float*)d_in[18];
    const float* b_cls  = (const float*)d_in[19];

    const int M = BSZ * SEQL;   // 8192

    float* ws = (float*)d_ws;
    float* t_buf   = ws;                  ws += (size_t)M * DM;        // 4.19M
    float* uz      = ws;                  ws += (size_t)M * 2048;      // 16.78M  (u/dt half + z half)
    float* uc      = ws;                  ws += (size_t)M * DI;        // 8.39M
    float* dtc     = ws;                  ws += (size_t)M * 32;        // 0.26M
    float* bcb     = ws;                  ws += (size_t)M * 32;        // 0.26M
    float* ssqb    = ws;                  ws += (size_t)M;             // 8K
    float* scratch = ws;                  ws += (size_t)M * DI / 2 * 2;// 4.19M fp32 words (xn_bf | part | uc_bf)
    float* wtin    = ws;                  ws += (size_t)NLAYERS * DM * 2048 / 2;  // 2.10M (bf16)
    float* wtout   = ws;                  ws += (size_t)NLAYERS * DI * DM / 2;    // 1.05M (bf16)
    float* poolp   = ws;                  ws += (size_t)128 * DM;      // 65K

    __hip_bfloat16* xn_bf = (__hip_bfloat16*)scratch;   // [M][512]
    float*          partb = scratch;                    // [KSPLIT][M][64]
    __hip_bfloat16* uc_bf = (__hip_bfloat16*)scratch;   // [M][1024]
    __hip_bfloat16* wtin_bf  = (__hip_bfloat16*)wtin;   // [L][2048][512]
    __hip_bfloat16* wtout_bf = (__hip_bfloat16*)wtout;  // [L][512][1024]

    embed_kernel<<<(M * DM + 255) / 256, 256, 0, stream>>>(x, W_inp, b_inp, t_buf);
    transpose_bf_kernel<<<dim3(DM / 32, 2048 / 32, NLAYERS), 256, 0, stream>>>(
        W_in, wtin_bf, DM, 2048, (size_t)DM * 2048);
    transpose_bf_kernel<<<dim3(DI / 32, DM / 32, NLAYERS), 256, 0, stream>>>(
        W_out, wtout_bf, DI, DM, (size_t)DI * DM);

    for (int i = 0; i < NLAYERS; i++) {
        ln_kernel<<<M, 256, 0, stream>>>(t_buf, ln_w + i * DM, ln_b + i * DM, xn_bf);
        gemm_mfma_kernel<false><<<dim3(M / 128, 2048 / 128), 256, 0, stream>>>(
            (const short*)xn_bf, (const short*)(wtin_bf + (size_t)i * DM * 2048),
            b_in + i * 2048, uz, M, 2048, DM);
        conv_kernel<<<(M * DI) / 256, 256, 0, stream>>>(
            uz, conv_w + (size_t)i * DI * 4, conv_b + i * DI, uc);
        gemm64_splitk_kernel<<<dim3(M / 64, KSPLIT), 256, 0, stream>>>(
            uc, W_x + (size_t)i * DI * 64, partb, M, DI);
        repack_kernel<<<M / 4, 256, 0, stream>>>(partb, dtc, bcb, ssqb, M);
        dt_kernel<<<(M * DI) / 256, 256, 0, stream>>>(
            dtc, W_dt + (size_t)i * DTR * DI, b_dt + i * DI, uz);
        scan_kernel<<<BSZ * DI / 16, 256, 0, stream>>>(
            uc, uz, bcb, ssqb, A_log + (size_t)i * DI * DST, D_skip + i * DI, uc_bf);
        gemm_mfma_kernel<true><<<dim3(M / 128, DM / 128), 256, 0, stream>>>(
            (const short*)uc_bf, (const short*)(wtout_bf + (size_t)i * DI * DM),
            b_out + i * DM, t_buf, M, DM, DI);
    }

    pool_kernel<<<128, 512, 0, stream>>>(t_buf, poolp);
    final_kernel<<<8, 512, 0, stream>>>(poolp, lnf_w, lnf_b, W_cls, b_cls, (float*)d_out);
}

// Round 4
// 1737.901 us; speedup vs baseline: 3.6207x; 1.0014x over previous
//
#include <hip/hip_runtime.h>
#include <hip/hip_bf16.h>
#include <math.h>

#define BSZ 8
#define SEQL 1024
#define DM 512
#define DI 1024
#define DST 16
#define DTR 32
#define NLAYERS 4
#define ALPHA_C 0.2f
#define LNEPS 1e-5f
#define CH 64          // scan LDS chunk length (t-steps)
#define KSPLIT 2       // split-K factor for the skinny N=64 GEMM

typedef __attribute__((ext_vector_type(8))) short short8;
typedef __attribute__((ext_vector_type(4))) float f32x4;

// async global->LDS, 16B per lane. LDS dest = wave-uniform base + lane*16.
__device__ __forceinline__ void gll16(const void* g, void* l) {
    __builtin_amdgcn_global_load_lds(
        (const __attribute__((address_space(1))) unsigned int*)g,
        (__attribute__((address_space(3))) unsigned int*)l, 16, 0, 0);
}

// DPP row_ror sum over rows of 16 lanes (rows align with our n-groups)
__device__ __forceinline__ float sum16(float x) {
    x += __int_as_float(__builtin_amdgcn_update_dpp(0, __float_as_int(x), 0x121, 0xf, 0xf, true));
    x += __int_as_float(__builtin_amdgcn_update_dpp(0, __float_as_int(x), 0x122, 0xf, 0xf, true));
    x += __int_as_float(__builtin_amdgcn_update_dpp(0, __float_as_int(x), 0x124, 0xf, 0xf, true));
    x += __int_as_float(__builtin_amdgcn_update_dpp(0, __float_as_int(x), 0x128, 0xf, 0xf, true));
    return x;
}

// ---------------- input embedding ----------------
__global__ __launch_bounds__(256) void embed_kernel(const float* __restrict__ x,
                                                    const float* __restrict__ Wi,
                                                    const float* __restrict__ bi,
                                                    float* __restrict__ t) {
    int idx = blockIdx.x * 256 + threadIdx.x;
    if (idx >= BSZ * SEQL * DM) return;
    int d  = idx & (DM - 1);
    int bl = idx >> 9;
    int l  = bl & (SEQL - 1);
    int b  = bl >> 10;
    const float* xb = x + (size_t)b * 3 * SEQL;
    float acc = bi[d];
    acc += xb[0 * SEQL + l] * Wi[0 * DM + d];
    acc += xb[1 * SEQL + l] * Wi[1 * DM + d];
    acc += xb[2 * SEQL + l] * Wi[2 * DM + d];
    t[idx] = acc;
}

// ---------------- layernorm over DM=512, writes bf16 ----------------
__global__ __launch_bounds__(256) void ln_kernel(const float* __restrict__ t,
                                                 const float* __restrict__ w,
                                                 const float* __restrict__ b,
                                                 __hip_bfloat16* __restrict__ xn) {
    int row = blockIdx.x;
    int tid = threadIdx.x;
    const float* r = t + (size_t)row * DM;
    float v0 = r[tid], v1 = r[tid + 256];
    __shared__ float sh[256], sh2[256];
    sh[tid]  = v0 + v1;
    sh2[tid] = v0 * v0 + v1 * v1;
    __syncthreads();
    for (int off = 128; off > 0; off >>= 1) {
        if (tid < off) { sh[tid] += sh[tid + off]; sh2[tid] += sh2[tid + off]; }
        __syncthreads();
    }
    float mu  = sh[0]  * (1.f / DM);
    float var = sh2[0] * (1.f / DM) - mu * mu;
    float rs  = rsqrtf(var + LNEPS);
    xn[(size_t)row * DM + tid]       = __float2bfloat16((v0 - mu) * rs * w[tid]       + b[tid]);
    xn[(size_t)row * DM + tid + 256] = __float2bfloat16((v1 - mu) * rs * w[tid + 256] + b[tid + 256]);
}

// ---------------- transpose + fp32->bf16: W[K][N] -> Wt[N][K], per layer (grid.z) ----------------
__global__ __launch_bounds__(256) void transpose_bf_kernel(const float* __restrict__ W,
                                                           __hip_bfloat16* __restrict__ Wt,
                                                           int K, int N, size_t lstride) {
    const float* Wl = W + (size_t)blockIdx.z * lstride;
    __hip_bfloat16* Wtl = Wt + (size_t)blockIdx.z * lstride;
    __shared__ float tile[32][33];
    int kk = blockIdx.x * 32, nn = blockIdx.y * 32;
    int tx = threadIdx.x & 31, ty = threadIdx.x >> 5;
#pragma unroll
    for (int i = 0; i < 32; i += 8)
        tile[ty + i][tx] = Wl[(size_t)(kk + ty + i) * N + nn + tx];
    __syncthreads();
#pragma unroll
    for (int i = 0; i < 32; i += 8)
        Wtl[(size_t)(nn + ty + i) * K + kk + tx] = __float2bfloat16(tile[tx][ty + i]);
}

// ---------------- bf16 MFMA GEMM: C = A[M,K] @ Bt[N,K]^T + bias (+=C if RES) ----------------
template <bool RES>
__global__ __launch_bounds__(256) void gemm_mfma_kernel(const short* __restrict__ A,
                                                        const short* __restrict__ Bt,
                                                        const float* __restrict__ bias,
                                                        float* __restrict__ C,
                                                        int M, int N, int K) {
    __shared__ __align__(16) short As[128 * 32];
    __shared__ __align__(16) short Bs[128 * 32];
    int tid = threadIdx.x;
    int w = tid >> 6, lane = tid & 63;
    int quad = lane >> 4, ml = lane & 15;
    int wm = w & 1, wn = w >> 1;
    const short* Ab = A + (size_t)blockIdx.x * 128 * K;
    const short* Bb = Bt + (size_t)blockIdx.y * 128 * K;
    f32x4 acc[4][4] = {};
    int s0 = tid, s1 = tid + 256;
    int r0 = s0 >> 2, c0 = (s0 & 3) ^ ((r0 >> 1) & 3);
    int r1 = s1 >> 2, c1 = (s1 & 3) ^ ((r1 >> 1) & 3);
    int aoff[4], boff[4];
#pragma unroll
    for (int t = 0; t < 4; t++) {
        int ra = wm * 64 + t * 16 + ml;
        aoff[t] = ra * 32 + (quad ^ ((ra >> 1) & 3)) * 8;
        int rb = wn * 64 + t * 16 + ml;
        boff[t] = rb * 32 + (quad ^ ((rb >> 1) & 3)) * 8;
    }
    for (int kk = 0; kk < K; kk += 32) {
        gll16(Ab + (size_t)r0 * K + kk + c0 * 8, As + (size_t)(w * 64) * 8);
        gll16(Ab + (size_t)r1 * K + kk + c1 * 8, As + (size_t)(256 + w * 64) * 8);
        gll16(Bb + (size_t)r0 * K + kk + c0 * 8, Bs + (size_t)(w * 64) * 8);
        gll16(Bb + (size_t)r1 * K + kk + c1 * 8, Bs + (size_t)(256 + w * 64) * 8);
        __syncthreads();
        short8 af[4], bfr[4];
#pragma unroll
        for (int t = 0; t < 4; t++) af[t]  = *(const short8*)&As[aoff[t]];
#pragma unroll
        for (int t = 0; t < 4; t++) bfr[t] = *(const short8*)&Bs[boff[t]];
#pragma unroll
        for (int mt = 0; mt < 4; mt++)
#pragma unroll
            for (int nt = 0; nt < 4; nt++)
                acc[mt][nt] = __builtin_amdgcn_mfma_f32_16x16x32_bf16(af[mt], bfr[nt], acc[mt][nt], 0, 0, 0);
        __syncthreads();
    }
#pragma unroll
    for (int mt = 0; mt < 4; mt++) {
#pragma unroll
        for (int nt = 0; nt < 4; nt++) {
            int n = blockIdx.y * 128 + wn * 64 + nt * 16 + ml;
            float bv = bias[n];
#pragma unroll
            for (int r = 0; r < 4; r++) {
                int m = blockIdx.x * 128 + wm * 64 + mt * 16 + quad * 4 + r;
                size_t off = (size_t)m * N + n;
                float v = acc[mt][nt][r] + bv;
                if (RES) v += C[off];
                C[off] = v;
            }
        }
    }
}

// ---------------- causal depthwise conv (D_CONV=4) + SiLU ----------------
__global__ __launch_bounds__(256) void conv_kernel(const float* __restrict__ uz,
                                                   const float* __restrict__ cw,
                                                   const float* __restrict__ cb,
                                                   float* __restrict__ uc) {
    int idx = blockIdx.x * 256 + threadIdx.x;
    int e  = idx & (DI - 1);
    int bl = idx >> 10;
    int l  = bl & (SEQL - 1);
    int b  = bl >> 10;
    const float* u = uz + (size_t)b * SEQL * 2048;
    float acc = cb[e];
#pragma unroll
    for (int k = 0; k < 4; k++) {
        int ll = l - 3 + k;
        float uv = (ll >= 0) ? u[(size_t)ll * 2048 + e] : 0.f;
        acc += uv * cw[e * 4 + k];
    }
    acc = acc / (1.f + expf(-acc));
    uc[idx] = acc;
}

// ---------------- fp32 GEMM 64-wide, split-K: part[ks][M][64] ----------------
__global__ __launch_bounds__(256) void gemm64_splitk_kernel(const float* __restrict__ A,
                                                            const float* __restrict__ Bg,
                                                            float* __restrict__ part,
                                                            int M, int K) {
    __shared__ float As[16][64];
    __shared__ float Bs[16][64];
    const int N = 64;
    int tid = threadIdx.x;
    int tn = tid & 15, tm = tid >> 4;
    int bm = blockIdx.x, ks = blockIdx.y;
    int k0 = ks * (K / KSPLIT), k1 = k0 + K / KSPLIT;
    const float* Ab = A + (size_t)bm * 64 * K;
    float acc[4][4] = {};
    for (int kk = k0; kk < k1; kk += 16) {
#pragma unroll
        for (int i = 0; i < 4; i++) {
            int e = tid + 256 * i;
            int m = e >> 4, k = e & 15;
            As[k][m] = Ab[(size_t)m * K + kk + k];
        }
#pragma unroll
        for (int i = 0; i < 4; i++) {
            int e = tid + 256 * i;
            int k = e >> 6, n = e & 63;
            Bs[k][n] = Bg[(size_t)(kk + k) * N + n];
        }
        __syncthreads();
#pragma unroll
        for (int k = 0; k < 16; k++) {
            float4 a  = *(const float4*)&As[k][tm * 4];
            float4 bv = *(const float4*)&Bs[k][tn * 4];
            float av[4] = {a.x, a.y, a.z, a.w};
            float bw[4] = {bv.x, bv.y, bv.z, bv.w};
#pragma unroll
            for (int i = 0; i < 4; i++)
#pragma unroll
                for (int j = 0; j < 4; j++) acc[i][j] += av[i] * bw[j];
        }
        __syncthreads();
    }
    int m0 = bm * 64 + tm * 4;
    int n0 = tn * 4;
#pragma unroll
    for (int i = 0; i < 4; i++)
#pragma unroll
        for (int j = 0; j < 4; j++)
            part[((size_t)ks * M + m0 + i) * 64 + n0 + j] = acc[i][j];
}

// ---------------- reduce split-K partials; emit dtc[M][32], BC[M][32] interleaved, ssq[M] ----------------
__global__ __launch_bounds__(256) void repack_kernel(const float* __restrict__ part,
                                                     float* __restrict__ dtc,
                                                     float* __restrict__ bc,
                                                     float* __restrict__ ssqb,
                                                     int M) {
    int m = blockIdx.x * 4 + (threadIdx.x >> 6);
    int j = threadIdx.x & 63;
    float v = 0.f;
#pragma unroll
    for (int ks = 0; ks < KSPLIT; ks++) v += part[((size_t)ks * M + m) * 64 + j];
    float s = sum16(v * v);        // row 3 (lanes 48..63) = sum of C^2
    if (j < 32) dtc[(size_t)m * 32 + j] = v;
    else if (j < 48) bc[(size_t)m * 32 + 2 * (j - 32)] = v;          // B_n -> even
    else {
        bc[(size_t)m * 32 + 2 * (j - 48) + 1] = v;                    // C_n -> odd
        if (j == 48) ssqb[m] = s;
    }
}

// ---------------- dt = softplus(dtc @ Wdt + bdt), written into u-half of uz ----------------
__global__ __launch_bounds__(256) void dt_kernel(const float* __restrict__ dtc,
                                                 const float* __restrict__ Wdt,
                                                 const float* __restrict__ bdt,
                                                 float* __restrict__ uzdt) {
    int idx = blockIdx.x * 256 + threadIdx.x;
    int e  = idx & (DI - 1);
    int bl = idx >> 10;
    const float* dr = dtc + (size_t)bl * 32;
    float acc = bdt[e];
#pragma unroll
    for (int r = 0; r < DTR; r++) acc += dr[r] * Wdt[r * DI + e];
    uzdt[(size_t)bl * 2048 + e] = (acc > 20.f) ? acc : log1pf(expf(acc));
}

// ---------------- scan v5: LDS-chunked (CH=64), register-batched 8-t prefetch ----------------
__device__ __forceinline__ void scan_stage(float* sBC, float* sDT, float* sU, float* sZ, float* sSQ,
                                           const float* __restrict__ ucb,
                                           const float* __restrict__ uzb,
                                           const float* __restrict__ bcp,
                                           const float* __restrict__ sqb,
                                           int e_base, int tid, int tc) {
    int w = tid >> 6;
    int t8 = tid >> 3, c8 = tid & 7;
    gll16(bcp + (size_t)(tc + t8) * 32 + c8 * 4,       sBC + w * 256);
    gll16(bcp + (size_t)(tc + 32 + t8) * 32 + c8 * 4,  sBC + 1024 + w * 256);
    int t4 = tid >> 2, c4 = tid & 3;
    gll16(uzb + (size_t)(tc + t4) * 2048 + e_base + c4 * 4,        sDT + w * 256);  // dt
    gll16(ucb + (size_t)(tc + t4) * 1024 + e_base + c4 * 4,        sU  + w * 256);  // u
    gll16(uzb + (size_t)(tc + t4) * 2048 + 1024 + e_base + c4 * 4, sZ  + w * 256);  // z
    if (tid < 16) gll16(sqb + tc + tid * 4, sSQ);
}

__device__ __forceinline__ void scan_flush(const float* yb, __hip_bfloat16* ob,
                                           int e_base, int tcp, int tid) {
#pragma unroll
    for (int r = 0; r < 2; r++) {
        int pid = r * 256 + tid;
        int t = pid >> 3, ep = pid & 7;
        float2 y2 = *(const float2*)&yb[t * 16 + ep * 2];
        __hip_bfloat162 v;
        v.x = __float2bfloat16(y2.x);
        v.y = __float2bfloat16(y2.y);
        *(__hip_bfloat162*)&ob[(size_t)(tcp + t) * DI + e_base + ep * 2] = v;
    }
}

__global__ __launch_bounds__(256) void scan_kernel(const float* __restrict__ uc,
                                                   const float* __restrict__ uz,     // dt in u-half, z in z-half
                                                   const float* __restrict__ bcb,
                                                   const float* __restrict__ ssqb,
                                                   const float* __restrict__ Alog,
                                                   const float* __restrict__ Dv,
                                                   __hip_bfloat16* __restrict__ out) {
    __shared__ __align__(16) float sBC[2][CH * 32];
    __shared__ __align__(16) float sDT[2][CH * 16];
    __shared__ __align__(16) float sU [2][CH * 16];
    __shared__ __align__(16) float sZ [2][CH * 16];
    __shared__ __align__(16) float sSQ[2][CH];
    __shared__ __align__(16) float yb [2][CH * 16];
    int tid = threadIdx.x;
    int g = tid >> 4, n = tid & 15;
    int b = blockIdx.x >> 6;
    int e_base = (blockIdx.x & 63) << 4;
    int e = e_base + g;
    float An = -__expf(Alog[e * DST + n]);
    float dv = Dv[e];
    const float* ucb = uc + (size_t)b * SEQL * DI;
    const float* uzb = uz + (size_t)b * SEQL * 2048;
    const float* bcp = bcb + (size_t)b * SEQL * 32;
    const float* sqb = ssqb + (size_t)b * SEQL;
    __hip_bfloat16* ob = out + (size_t)b * SEQL * DI;
    float h = 0.f;
    scan_stage(sBC[0], sDT[0], sU[0], sZ[0], sSQ[0], ucb, uzb, bcp, sqb, e_base, tid, 0);
    int buf = 0;
    for (int c = 0; c < SEQL / CH; c++) {
        int tc = c * CH;
        __syncthreads();   // drains stage(c)'s async loads + prev chunk's yb writes
        if (c + 1 < SEQL / CH)
            scan_stage(sBC[buf ^ 1], sDT[buf ^ 1], sU[buf ^ 1], sZ[buf ^ 1], sSQ[buf ^ 1],
                       ucb, uzb, bcp, sqb, e_base, tid, tc + CH);
        if (c > 0)
            scan_flush(yb[buf ^ 1], ob, e_base, tc - CH, tid);
        const float* pBC = sBC[buf];
        const float* pDT = sDT[buf];
        const float* pU  = sU[buf];
        const float* pZ  = sZ[buf];
        const float* pSQ = sSQ[buf];
        float* pY = yb[buf];
        for (int ts = 0; ts < CH; ts += 8) {
            float2 bc8[8];
            float dt8[8], u8[8];
#pragma unroll
            for (int j = 0; j < 8; j++) {
                bc8[j] = *(const float2*)&pBC[(ts + j) * 32 + n * 2];
                dt8[j] = pDT[(ts + j) * 16 + g];
                u8[j]  = pU[(ts + j) * 16 + g];
            }
            float a8[8], w8[8];
#pragma unroll
            for (int j = 0; j < 8; j++) {
                a8[j] = __expf(dt8[j] * An);
                w8[j] = dt8[j] * u8[j] * bc8[j].x;
            }
#pragma unroll
            for (int j = 0; j < 8; j++) {
                h = fmaf(a8[j], h, w8[j]);
                float p = sum16(h * bc8[j].y);
                float aes = ALPHA_C * (u8[j] - p);
                h = fmaf(aes, bc8[j].y, h);
                if (n == 0) {
                    float y = p + aes * pSQ[ts + j] + dv * u8[j];
                    float zv = pZ[(ts + j) * 16 + g];
                    float sz = zv / (1.f + __expf(-zv));
                    pY[(ts + j) * 16 + g] = y * sz;
                }
            }
        }
        buf ^= 1;
    }
    __syncthreads();
    scan_flush(yb[buf ^ 1], ob, e_base, SEQL - CH, tid);
}

// ---------------- mean-pool partials ----------------
__global__ __launch_bounds__(512) void pool_kernel(const float* __restrict__ t,
                                                   float* __restrict__ part) {
    int b = blockIdx.x >> 4;
    int c = blockIdx.x & 15;
    int d = threadIdx.x;
    const float* tb = t + ((size_t)b * SEQL + c * 64) * DM + d;
    float s = 0.f;
    for (int l = 0; l < 64; l++) s += tb[(size_t)l * DM];
    part[(size_t)blockIdx.x * DM + d] = s;
}

// ---------------- final: mean, layernorm, classifier ----------------
__global__ __launch_bounds__(512) void final_kernel(const float* __restrict__ part,
                                                    const float* __restrict__ lw,
                                                    const float* __restrict__ lb,
                                                    const float* __restrict__ Wc,
                                                    const float* __restrict__ bc,
                                                    float* __restrict__ out) {
    int b = blockIdx.x;
    int d = threadIdx.x;
    float v = 0.f;
    for (int c = 0; c < 16; c++) v += part[((size_t)b * 16 + c) * DM + d];
    v *= (1.f / SEQL);
    __shared__ float sh[512], sh2[512], nd[512];
    sh[d] = v; sh2[d] = v * v;
    __syncthreads();
    for (int off = 256; off > 0; off >>= 1) {
        if (d < off) { sh[d] += sh[d + off]; sh2[d] += sh2[d + off]; }
        __syncthreads();
    }
    float mu  = sh[0]  * (1.f / DM);
    float var = sh2[0] * (1.f / DM) - mu * mu;
    float rs  = rsqrtf(var + LNEPS);
    nd[d] = (v - mu) * rs * lw[d] + lb[d];
    __syncthreads();
    if (d < 10) {
        float acc = bc[d];
        for (int k = 0; k < DM; k++) acc += nd[k] * Wc[k * 10 + d];
        out[b * 10 + d] = acc;
    }
}

extern "C" void kernel_launch(void* const* d_in, const int* in_sizes, int n_in,
                              void* d_out, int out_size, void* d_ws, size_t ws_size,
                              hipStream_t stream) {
    const float* x      = (const float*)d_in[0];
    const float* W_inp  = (const float*)d_in[1];
    const float* b_inp  = (const float*)d_in[2];
    const float* W_in   = (const float*)d_in[3];
    const float* b_in   = (const float*)d_in[4];
    const float* conv_w = (const float*)d_in[5];
    const float* conv_b = (const float*)d_in[6];
    const float* W_x    = (const float*)d_in[7];
    const float* W_dt   = (const float*)d_in[8];
    const float* b_dt   = (const float*)d_in[9];
    const float* A_log  = (const float*)d_in[10];
    const float* D_skip = (const float*)d_in[11];
    const float* W_out  = (const float*)d_in[12];
    const float* b_out  = (const float*)d_in[13];
    const float* ln_w   = (const float*)d_in[14];
    const float* ln_b   = (const float*)d_in[15];
    const float* lnf_w  = (const float*)d_in[16];
    const float* lnf_b  = (const float*)d_in[17];
    const float* W_cls  = (const float*)d_in[18];
    const float* b_cls  = (const float*)d_in[19];

    const int M = BSZ * SEQL;   // 8192

    float* ws = (float*)d_ws;
    float* t_buf   = ws;                  ws += (size_t)M * DM;
    float* uz      = ws;                  ws += (size_t)M * 2048;
    float* uc      = ws;                  ws += (size_t)M * DI;
    float* dtc     = ws;                  ws += (size_t)M * 32;
    float* bcb     = ws;                  ws += (size_t)M * 32;
    float* ssqb    = ws;                  ws += (size_t)M;
    float* scratch = ws;                  ws += (size_t)M * DI / 2 * 2;
    float* wtin    = ws;                  ws += (size_t)NLAYERS * DM * 2048 / 2;
    float* wtout   = ws;                  ws += (size_t)NLAYERS * DI * DM / 2;
    float* poolp   = ws;                  ws += (size_t)128 * DM;

    __hip_bfloat16* xn_bf = (__hip_bfloat16*)scratch;   // [M][512]
    float*          partb = scratch;                    // [KSPLIT][M][64]
    __hip_bfloat16* uc_bf = (__hip_bfloat16*)scratch;   // [M][1024]
    __hip_bfloat16* wtin_bf  = (__hip_bfloat16*)wtin;   // [L][2048][512]
    __hip_bfloat16* wtout_bf = (__hip_bfloat16*)wtout;  // [L][512][1024]

    embed_kernel<<<(M * DM + 255) / 256, 256, 0, stream>>>(x, W_inp, b_inp, t_buf);
    transpose_bf_kernel<<<dim3(DM / 32, 2048 / 32, NLAYERS), 256, 0, stream>>>(
        W_in, wtin_bf, DM, 2048, (size_t)DM * 2048);
    transpose_bf_kernel<<<dim3(DI / 32, DM / 32, NLAYERS), 256, 0, stream>>>(
        W_out, wtout_bf, DI, DM, (size_t)DI * DM);

    for (int i = 0; i < NLAYERS; i++) {
        ln_kernel<<<M, 256, 0, stream>>>(t_buf, ln_w + i * DM, ln_b + i * DM, xn_bf);
        gemm_mfma_kernel<false><<<dim3(M / 128, 2048 / 128), 256, 0, stream>>>(
            (const short*)xn_bf, (const short*)(wtin_bf + (size_t)i * DM * 2048),
            b_in + i * 2048, uz, M, 2048, DM);
        conv_kernel<<<(M * DI) / 256, 256, 0, stream>>>(
            uz, conv_w + (size_t)i * DI * 4, conv_b + i * DI, uc);
        gemm64_splitk_kernel<<<dim3(M / 64, KSPLIT), 256, 0, stream>>>(
            uc, W_x + (size_t)i * DI * 64, partb, M, DI);
        repack_kernel<<<M / 4, 256, 0, stream>>>(partb, dtc, bcb, ssqb, M);
        dt_kernel<<<(M * DI) / 256, 256, 0, stream>>>(
            dtc, W_dt + (size_t)i * DTR * DI, b_dt + i * DI, uz);
        scan_kernel<<<BSZ * DI / 16, 256, 0, stream>>>(
            uc, uz, bcb, ssqb, A_log + (size_t)i * DI * DST, D_skip + i * DI, uc_bf);
        gemm_mfma_kernel<true><<<dim3(M / 128, DM / 128), 256, 0, stream>>>(
            (const short*)uc_bf, (const short*)(wtout_bf + (size_t)i * DI * DM),
            b_out + i * DM, t_buf, M, DM, DI);
    }

    pool_kernel<<<128, 512, 0, stream>>>(t_buf, poolp);
    final_kernel<<<8, 512, 0, stream>>>(poolp, lnf_w, lnf_b, W_cls, b_cls, (float*)d_out);
}

// Round 5
// 1388.547 us; speedup vs baseline: 4.5317x; 1.2516x over previous
//
#include <hip/hip_runtime.h>
#include <hip/hip_bf16.h>
#include <math.h>

#define BSZ 8
#define SEQL 1024
#define DM 512
#define DI 1024
#define DST 16
#define DTR 32
#define NLAYERS 4
#define ALPHA_C 0.2f
#define LNEPS 1e-5f
#define CH 64          // scan LDS chunk length (t-steps)
#define KSPLIT 2       // split-K factor for the skinny N=64 GEMM

typedef __attribute__((ext_vector_type(8))) short short8;
typedef __attribute__((ext_vector_type(4))) float f32x4;

// async global->LDS, 16B per lane. LDS dest = wave-uniform base + lane*16.
__device__ __forceinline__ void gll16(const void* g, void* l) {
    __builtin_amdgcn_global_load_lds(
        (const __attribute__((address_space(1))) unsigned int*)g,
        (__attribute__((address_space(3))) unsigned int*)l, 16, 0, 0);
}

// DPP row_ror butterfly sum over rows of 16 lanes; result uniform in all 16 lanes
__device__ __forceinline__ float sum16(float x) {
    x += __int_as_float(__builtin_amdgcn_update_dpp(0, __float_as_int(x), 0x121, 0xf, 0xf, true));
    x += __int_as_float(__builtin_amdgcn_update_dpp(0, __float_as_int(x), 0x122, 0xf, 0xf, true));
    x += __int_as_float(__builtin_amdgcn_update_dpp(0, __float_as_int(x), 0x124, 0xf, 0xf, true));
    x += __int_as_float(__builtin_amdgcn_update_dpp(0, __float_as_int(x), 0x128, 0xf, 0xf, true));
    return x;
}

// ---------------- input embedding ----------------
__global__ __launch_bounds__(256) void embed_kernel(const float* __restrict__ x,
                                                    const float* __restrict__ Wi,
                                                    const float* __restrict__ bi,
                                                    float* __restrict__ t) {
    int idx = blockIdx.x * 256 + threadIdx.x;
    if (idx >= BSZ * SEQL * DM) return;
    int d  = idx & (DM - 1);
    int bl = idx >> 9;
    int l  = bl & (SEQL - 1);
    int b  = bl >> 10;
    const float* xb = x + (size_t)b * 3 * SEQL;
    float acc = bi[d];
    acc += xb[0 * SEQL + l] * Wi[0 * DM + d];
    acc += xb[1 * SEQL + l] * Wi[1 * DM + d];
    acc += xb[2 * SEQL + l] * Wi[2 * DM + d];
    t[idx] = acc;
}

// ---------------- layernorm over DM=512, writes bf16 ----------------
__global__ __launch_bounds__(256) void ln_kernel(const float* __restrict__ t,
                                                 const float* __restrict__ w,
                                                 const float* __restrict__ b,
                                                 __hip_bfloat16* __restrict__ xn) {
    int row = blockIdx.x;
    int tid = threadIdx.x;
    const float* r = t + (size_t)row * DM;
    float v0 = r[tid], v1 = r[tid + 256];
    __shared__ float sh[256], sh2[256];
    sh[tid]  = v0 + v1;
    sh2[tid] = v0 * v0 + v1 * v1;
    __syncthreads();
    for (int off = 128; off > 0; off >>= 1) {
        if (tid < off) { sh[tid] += sh[tid + off]; sh2[tid] += sh2[tid + off]; }
        __syncthreads();
    }
    float mu  = sh[0]  * (1.f / DM);
    float var = sh2[0] * (1.f / DM) - mu * mu;
    float rs  = rsqrtf(var + LNEPS);
    xn[(size_t)row * DM + tid]       = __float2bfloat16((v0 - mu) * rs * w[tid]       + b[tid]);
    xn[(size_t)row * DM + tid + 256] = __float2bfloat16((v1 - mu) * rs * w[tid + 256] + b[tid + 256]);
}

// ---------------- transpose + fp32->bf16: W[K][N] -> Wt[N][K], per layer (grid.z) ----------------
__global__ __launch_bounds__(256) void transpose_bf_kernel(const float* __restrict__ W,
                                                           __hip_bfloat16* __restrict__ Wt,
                                                           int K, int N, size_t lstride) {
    const float* Wl = W + (size_t)blockIdx.z * lstride;
    __hip_bfloat16* Wtl = Wt + (size_t)blockIdx.z * lstride;
    __shared__ float tile[32][33];
    int kk = blockIdx.x * 32, nn = blockIdx.y * 32;
    int tx = threadIdx.x & 31, ty = threadIdx.x >> 5;
#pragma unroll
    for (int i = 0; i < 32; i += 8)
        tile[ty + i][tx] = Wl[(size_t)(kk + ty + i) * N + nn + tx];
    __syncthreads();
#pragma unroll
    for (int i = 0; i < 32; i += 8)
        Wtl[(size_t)(nn + ty + i) * K + kk + tx] = __float2bfloat16(tile[tx][ty + i]);
}

// ---------------- bf16 MFMA GEMM: C = A[M,K] @ Bt[N,K]^T + bias (+=C if RES) ----------------
template <bool RES>
__global__ __launch_bounds__(256) void gemm_mfma_kernel(const short* __restrict__ A,
                                                        const short* __restrict__ Bt,
                                                        const float* __restrict__ bias,
                                                        float* __restrict__ C,
                                                        int M, int N, int K) {
    __shared__ __align__(16) short As[128 * 32];
    __shared__ __align__(16) short Bs[128 * 32];
    int tid = threadIdx.x;
    int w = tid >> 6, lane = tid & 63;
    int quad = lane >> 4, ml = lane & 15;
    int wm = w & 1, wn = w >> 1;
    const short* Ab = A + (size_t)blockIdx.x * 128 * K;
    const short* Bb = Bt + (size_t)blockIdx.y * 128 * K;
    f32x4 acc[4][4] = {};
    int s0 = tid, s1 = tid + 256;
    int r0 = s0 >> 2, c0 = (s0 & 3) ^ ((r0 >> 1) & 3);
    int r1 = s1 >> 2, c1 = (s1 & 3) ^ ((r1 >> 1) & 3);
    int aoff[4], boff[4];
#pragma unroll
    for (int t = 0; t < 4; t++) {
        int ra = wm * 64 + t * 16 + ml;
        aoff[t] = ra * 32 + (quad ^ ((ra >> 1) & 3)) * 8;
        int rb = wn * 64 + t * 16 + ml;
        boff[t] = rb * 32 + (quad ^ ((rb >> 1) & 3)) * 8;
    }
    for (int kk = 0; kk < K; kk += 32) {
        gll16(Ab + (size_t)r0 * K + kk + c0 * 8, As + (size_t)(w * 64) * 8);
        gll16(Ab + (size_t)r1 * K + kk + c1 * 8, As + (size_t)(256 + w * 64) * 8);
        gll16(Bb + (size_t)r0 * K + kk + c0 * 8, Bs + (size_t)(w * 64) * 8);
        gll16(Bb + (size_t)r1 * K + kk + c1 * 8, Bs + (size_t)(256 + w * 64) * 8);
        __syncthreads();
        short8 af[4], bfr[4];
#pragma unroll
        for (int t = 0; t < 4; t++) af[t]  = *(const short8*)&As[aoff[t]];
#pragma unroll
        for (int t = 0; t < 4; t++) bfr[t] = *(const short8*)&Bs[boff[t]];
#pragma unroll
        for (int mt = 0; mt < 4; mt++)
#pragma unroll
            for (int nt = 0; nt < 4; nt++)
                acc[mt][nt] = __builtin_amdgcn_mfma_f32_16x16x32_bf16(af[mt], bfr[nt], acc[mt][nt], 0, 0, 0);
        __syncthreads();
    }
#pragma unroll
    for (int mt = 0; mt < 4; mt++) {
#pragma unroll
        for (int nt = 0; nt < 4; nt++) {
            int n = blockIdx.y * 128 + wn * 64 + nt * 16 + ml;
            float bv = bias[n];
#pragma unroll
            for (int r = 0; r < 4; r++) {
                int m = blockIdx.x * 128 + wm * 64 + mt * 16 + quad * 4 + r;
                size_t off = (size_t)m * N + n;
                float v = acc[mt][nt][r] + bv;
                if (RES) v += C[off];
                C[off] = v;
            }
        }
    }
}

// ---------------- causal depthwise conv (D_CONV=4) + SiLU ----------------
__global__ __launch_bounds__(256) void conv_kernel(const float* __restrict__ uz,
                                                   const float* __restrict__ cw,
                                                   const float* __restrict__ cb,
                                                   float* __restrict__ uc) {
    int idx = blockIdx.x * 256 + threadIdx.x;
    int e  = idx & (DI - 1);
    int bl = idx >> 10;
    int l  = bl & (SEQL - 1);
    int b  = bl >> 10;
    const float* u = uz + (size_t)b * SEQL * 2048;
    float acc = cb[e];
#pragma unroll
    for (int k = 0; k < 4; k++) {
        int ll = l - 3 + k;
        float uv = (ll >= 0) ? u[(size_t)ll * 2048 + e] : 0.f;
        acc += uv * cw[e * 4 + k];
    }
    acc = acc / (1.f + expf(-acc));
    uc[idx] = acc;
}

// ---------------- fp32 GEMM 64-wide, split-K: part[ks][M][64] ----------------
__global__ __launch_bounds__(256) void gemm64_splitk_kernel(const float* __restrict__ A,
                                                            const float* __restrict__ Bg,
                                                            float* __restrict__ part,
                                                            int M, int K) {
    __shared__ float As[16][64];
    __shared__ float Bs[16][64];
    const int N = 64;
    int tid = threadIdx.x;
    int tn = tid & 15, tm = tid >> 4;
    int bm = blockIdx.x, ks = blockIdx.y;
    int k0 = ks * (K / KSPLIT), k1 = k0 + K / KSPLIT;
    const float* Ab = A + (size_t)bm * 64 * K;
    float acc[4][4] = {};
    for (int kk = k0; kk < k1; kk += 16) {
#pragma unroll
        for (int i = 0; i < 4; i++) {
            int e = tid + 256 * i;
            int m = e >> 4, k = e & 15;
            As[k][m] = Ab[(size_t)m * K + kk + k];
        }
#pragma unroll
        for (int i = 0; i < 4; i++) {
            int e = tid + 256 * i;
            int k = e >> 6, n = e & 63;
            Bs[k][n] = Bg[(size_t)(kk + k) * N + n];
        }
        __syncthreads();
#pragma unroll
        for (int k = 0; k < 16; k++) {
            float4 a  = *(const float4*)&As[k][tm * 4];
            float4 bv = *(const float4*)&Bs[k][tn * 4];
            float av[4] = {a.x, a.y, a.z, a.w};
            float bw[4] = {bv.x, bv.y, bv.z, bv.w};
#pragma unroll
            for (int i = 0; i < 4; i++)
#pragma unroll
                for (int j = 0; j < 4; j++) acc[i][j] += av[i] * bw[j];
        }
        __syncthreads();
    }
    int m0 = bm * 64 + tm * 4;
    int n0 = tn * 4;
#pragma unroll
    for (int i = 0; i < 4; i++)
#pragma unroll
        for (int j = 0; j < 4; j++)
            part[((size_t)ks * M + m0 + i) * 64 + n0 + j] = acc[i][j];
}

// ---------------- reduce split-K partials; emit dtc[M][32], BC[M][32] interleaved, ssq[M] ----------------
__global__ __launch_bounds__(256) void repack_kernel(const float* __restrict__ part,
                                                     float* __restrict__ dtc,
                                                     float* __restrict__ bc,
                                                     float* __restrict__ ssqb,
                                                     int M) {
    int m = blockIdx.x * 4 + (threadIdx.x >> 6);
    int j = threadIdx.x & 63;
    float v = 0.f;
#pragma unroll
    for (int ks = 0; ks < KSPLIT; ks++) v += part[((size_t)ks * M + m) * 64 + j];
    float s = sum16(v * v);        // row 3 (lanes 48..63) = sum of C^2
    if (j < 32) dtc[(size_t)m * 32 + j] = v;
    else if (j < 48) bc[(size_t)m * 32 + 2 * (j - 32)] = v;          // B_n -> even
    else {
        bc[(size_t)m * 32 + 2 * (j - 48) + 1] = v;                    // C_n -> odd
        if (j == 48) ssqb[m] = s;
    }
}

// ---------------- dt = softplus(dtc @ Wdt + bdt), written into u-half of uz ----------------
__global__ __launch_bounds__(256) void dt_kernel(const float* __restrict__ dtc,
                                                 const float* __restrict__ Wdt,
                                                 const float* __restrict__ bdt,
                                                 float* __restrict__ uzdt) {
    int idx = blockIdx.x * 256 + threadIdx.x;
    int e  = idx & (DI - 1);
    int bl = idx >> 10;
    const float* dr = dtc + (size_t)bl * 32;
    float acc = bdt[e];
#pragma unroll
    for (int r = 0; r < DTR; r++) acc += dr[r] * Wdt[r * DI + e];
    uzdt[(size_t)bl * 2048 + e] = (acc > 20.f) ? acc : log1pf(expf(acc));
}

// ---------------- scan v6: LDS-chunked, minimal-issue inner loop ----------------
// Key: after sum16, p/es/y are uniform across the 16 n-lanes -> compute y in all
// lanes (no divergent epilogue); lane n captures y at t%16==n via cndmask; silu
// gating + yb write happen once per 16 t, unconditionally.
__device__ __forceinline__ void scan_stage(float* sBC, float* sDT, float* sU, float* sZ, float* sSQ,
                                           const float* __restrict__ ucb,
                                           const float* __restrict__ uzb,
                                           const float* __restrict__ bcp,
                                           const float* __restrict__ sqb,
                                           int e_base, int tid, int tc) {
    int w = tid >> 6;
    int t8 = tid >> 3, c8 = tid & 7;
    gll16(bcp + (size_t)(tc + t8) * 32 + c8 * 4,       sBC + w * 256);
    gll16(bcp + (size_t)(tc + 32 + t8) * 32 + c8 * 4,  sBC + 1024 + w * 256);
    int t4 = tid >> 2, c4 = tid & 3;
    gll16(uzb + (size_t)(tc + t4) * 2048 + e_base + c4 * 4,        sDT + w * 256);  // dt
    gll16(ucb + (size_t)(tc + t4) * 1024 + e_base + c4 * 4,        sU  + w * 256);  // u
    gll16(uzb + (size_t)(tc + t4) * 2048 + 1024 + e_base + c4 * 4, sZ  + w * 256);  // z
    if (tid < 16) gll16(sqb + tc + tid * 4, sSQ);
}

__device__ __forceinline__ void scan_flush(const float* yb, __hip_bfloat16* ob,
                                           int e_base, int tcp, int tid) {
#pragma unroll
    for (int r = 0; r < 2; r++) {
        int pid = r * 256 + tid;
        int t = pid >> 3, ep = pid & 7;
        float2 y2 = *(const float2*)&yb[t * 16 + ep * 2];
        __hip_bfloat162 v;
        v.x = __float2bfloat16(y2.x);
        v.y = __float2bfloat16(y2.y);
        *(__hip_bfloat162*)&ob[(size_t)(tcp + t) * DI + e_base + ep * 2] = v;
    }
}

__global__ __launch_bounds__(256) void scan_kernel(const float* __restrict__ uc,
                                                   const float* __restrict__ uz,     // dt in u-half, z in z-half
                                                   const float* __restrict__ bcb,
                                                   const float* __restrict__ ssqb,
                                                   const float* __restrict__ Alog,
                                                   const float* __restrict__ Dv,
                                                   __hip_bfloat16* __restrict__ out) {
    __shared__ __align__(16) float sBC[2][CH * 32];
    __shared__ __align__(16) float sDT[2][CH * 16];
    __shared__ __align__(16) float sU [2][CH * 16];
    __shared__ __align__(16) float sZ [2][CH * 16];
    __shared__ __align__(16) float sSQ[2][CH];
    __shared__ __align__(16) float yb [2][CH * 16];
    int tid = threadIdx.x;
    int g = tid >> 4, n = tid & 15;
    int b = blockIdx.x >> 6;
    int e_base = (blockIdx.x & 63) << 4;
    int e = e_base + g;
    float An = -__expf(Alog[e * DST + n]);
    float dv = Dv[e];
    const float* ucb = uc + (size_t)b * SEQL * DI;
    const float* uzb = uz + (size_t)b * SEQL * 2048;
    const float* bcp = bcb + (size_t)b * SEQL * 32;
    const float* sqb = ssqb + (size_t)b * SEQL;
    __hip_bfloat16* ob = out + (size_t)b * SEQL * DI;
    float h = 0.f;
    scan_stage(sBC[0], sDT[0], sU[0], sZ[0], sSQ[0], ucb, uzb, bcp, sqb, e_base, tid, 0);
    int buf = 0;
    for (int c = 0; c < SEQL / CH; c++) {
        int tc = c * CH;
        __syncthreads();   // drains stage(c)'s async loads + prev chunk's yb writes
        if (c + 1 < SEQL / CH)
            scan_stage(sBC[buf ^ 1], sDT[buf ^ 1], sU[buf ^ 1], sZ[buf ^ 1], sSQ[buf ^ 1],
                       ucb, uzb, bcp, sqb, e_base, tid, tc + CH);
        if (c > 0)
            scan_flush(yb[buf ^ 1], ob, e_base, tc - CH, tid);
        const float* pBC = sBC[buf];
        const float* pDT = sDT[buf];
        const float* pU  = sU[buf];
        const float* pZ  = sZ[buf];
        const float* pSQ = sSQ[buf];
        float* pY = yb[buf];
        for (int ts = 0; ts < CH; ts += 16) {
            float yc = 0.f;
#pragma unroll
            for (int j = 0; j < 16; j++) {
                int t = ts + j;
                float2 bcv = *(const float2*)&pBC[t * 32 + n * 2];   // (B_n, C_n)
                float dtv = pDT[t * 16 + g];
                float uv  = pU[t * 16 + g];
                float sq  = pSQ[t];
                float a = __expf(dtv * An);
                h = fmaf(a, h, dtv * uv * bcv.x);
                float p = sum16(h * bcv.y);          // uniform over 16 lanes
                float aes = ALPHA_C * (uv - p);
                h = fmaf(aes, bcv.y, h);
                float y = fmaf(dv, uv, fmaf(aes, sq, p));
                yc = (n == j) ? y : yc;              // compile-time j: cmp+cndmask
            }
            int tl = ts + n;
            float zv = pZ[tl * 16 + g];
            float sz = zv / (1.f + __expf(-zv));
            pY[tl * 16 + g] = yc * sz;
        }
        buf ^= 1;
    }
    __syncthreads();
    scan_flush(yb[buf ^ 1], ob, e_base, SEQL - CH, tid);
}

// ---------------- mean-pool partials ----------------
__global__ __launch_bounds__(512) void pool_kernel(const float* __restrict__ t,
                                                   float* __restrict__ part) {
    int b = blockIdx.x >> 4;
    int c = blockIdx.x & 15;
    int d = threadIdx.x;
    const float* tb = t + ((size_t)b * SEQL + c * 64) * DM + d;
    float s = 0.f;
    for (int l = 0; l < 64; l++) s += tb[(size_t)l * DM];
    part[(size_t)blockIdx.x * DM + d] = s;
}

// ---------------- final: mean, layernorm, classifier ----------------
__global__ __launch_bounds__(512) void final_kernel(const float* __restrict__ part,
                                                    const float* __restrict__ lw,
                                                    const float* __restrict__ lb,
                                                    const float* __restrict__ Wc,
                                                    const float* __restrict__ bc,
                                                    float* __restrict__ out) {
    int b = blockIdx.x;
    int d = threadIdx.x;
    float v = 0.f;
    for (int c = 0; c < 16; c++) v += part[((size_t)b * 16 + c) * DM + d];
    v *= (1.f / SEQL);
    __shared__ float sh[512], sh2[512], nd[512];
    sh[d] = v; sh2[d] = v * v;
    __syncthreads();
    for (int off = 256; off > 0; off >>= 1) {
        if (d < off) { sh[d] += sh[d + off]; sh2[d] += sh2[d + off]; }
        __syncthreads();
    }
    float mu  = sh[0]  * (1.f / DM);
    float var = sh2[0] * (1.f / DM) - mu * mu;
    float rs  = rsqrtf(var + LNEPS);
    nd[d] = (v - mu) * rs * lw[d] + lb[d];
    __syncthreads();
    if (d < 10) {
        float acc = bc[d];
        for (int k = 0; k < DM; k++) acc += nd[k] * Wc[k * 10 + d];
        out[b * 10 + d] = acc;
    }
}

extern "C" void kernel_launch(void* const* d_in, const int* in_sizes, int n_in,
                              void* d_out, int out_size, void* d_ws, size_t ws_size,
                              hipStream_t stream) {
    const float* x      = (const float*)d_in[0];
    const float* W_inp  = (const float*)d_in[1];
    const float* b_inp  = (const float*)d_in[2];
    const float* W_in   = (const float*)d_in[3];
    const float* b_in   = (const float*)d_in[4];
    const float* conv_w = (const float*)d_in[5];
    const float* conv_b = (const float*)d_in[6];
    const float* W_x    = (const float*)d_in[7];
    const float* W_dt   = (const float*)d_in[8];
    const float* b_dt   = (const float*)d_in[9];
    const float* A_log  = (const float*)d_in[10];
    const float* D_skip = (const float*)d_in[11];
    const float* W_out  = (const float*)d_in[12];
    const float* b_out  = (const float*)d_in[13];
    const float* ln_w   = (const float*)d_in[14];
    const float* ln_b   = (const float*)d_in[15];
    const float* lnf_w  = (const float*)d_in[16];
    const float* lnf_b  = (const float*)d_in[17];
    const float* W_cls  = (const float*)d_in[18];
    const float* b_cls  = (const float*)d_in[19];

    const int M = BSZ * SEQL;   // 8192

    float* ws = (float*)d_ws;
    float* t_buf   = ws;                  ws += (size_t)M * DM;
    float* uz      = ws;                  ws += (size_t)M * 2048;
    float* uc      = ws;                  ws += (size_t)M * DI;
    float* dtc     = ws;                  ws += (size_t)M * 32;
    float* bcb     = ws;                  ws += (size_t)M * 32;
    float* ssqb    = ws;                  ws += (size_t)M;
    float* scratch = ws;                  ws += (size_t)M * DI / 2 * 2;
    float* wtin    = ws;                  ws += (size_t)NLAYERS * DM * 2048 / 2;
    float* wtout   = ws;                  ws += (size_t)NLAYERS * DI * DM / 2;
    float* poolp   = ws;                  ws += (size_t)128 * DM;

    __hip_bfloat16* xn_bf = (__hip_bfloat16*)scratch;   // [M][512]
    float*          partb = scratch;                    // [KSPLIT][M][64]
    __hip_bfloat16* uc_bf = (__hip_bfloat16*)scratch;   // [M][1024]
    __hip_bfloat16* wtin_bf  = (__hip_bfloat16*)wtin;   // [L][2048][512]
    __hip_bfloat16* wtout_bf = (__hip_bfloat16*)wtout;  // [L][512][1024]

    embed_kernel<<<(M * DM + 255) / 256, 256, 0, stream>>>(x, W_inp, b_inp, t_buf);
    transpose_bf_kernel<<<dim3(DM / 32, 2048 / 32, NLAYERS), 256, 0, stream>>>(
        W_in, wtin_bf, DM, 2048, (size_t)DM * 2048);
    transpose_bf_kernel<<<dim3(DI / 32, DM / 32, NLAYERS), 256, 0, stream>>>(
        W_out, wtout_bf, DI, DM, (size_t)DI * DM);

    for (int i = 0; i < NLAYERS; i++) {
        ln_kernel<<<M, 256, 0, stream>>>(t_buf, ln_w + i * DM, ln_b + i * DM, xn_bf);
        gemm_mfma_kernel<false><<<dim3(M / 128, 2048 / 128), 256, 0, stream>>>(
            (const short*)xn_bf, (const short*)(wtin_bf + (size_t)i * DM * 2048),
            b_in + i * 2048, uz, M, 2048, DM);
        conv_kernel<<<(M * DI) / 256, 256, 0, stream>>>(
            uz, conv_w + (size_t)i * DI * 4, conv_b + i * DI, uc);
        gemm64_splitk_kernel<<<dim3(M / 64, KSPLIT), 256, 0, stream>>>(
            uc, W_x + (size_t)i * DI * 64, partb, M, DI);
        repack_kernel<<<M / 4, 256, 0, stream>>>(partb, dtc, bcb, ssqb, M);
        dt_kernel<<<(M * DI) / 256, 256, 0, stream>>>(
            dtc, W_dt + (size_t)i * DTR * DI, b_dt + i * DI, uz);
        scan_kernel<<<BSZ * DI / 16, 256, 0, stream>>>(
            uc, uz, bcb, ssqb, A_log + (size_t)i * DI * DST, D_skip + i * DI, uc_bf);
        gemm_mfma_kernel<true><<<dim3(M / 128, DM / 128), 256, 0, stream>>>(
            (const short*)uc_bf, (const short*)(wtout_bf + (size_t)i * DI * DM),
            b_out + i * DM, t_buf, M, DM, DI);
    }

    pool_kernel<<<128, 512, 0, stream>>>(t_buf, poolp);
    final_kernel<<<8, 512, 0, stream>>>(poolp, lnf_w, lnf_b, W_cls, b_cls, (float*)d_out);
}

// Round 6
// 1366.477 us; speedup vs baseline: 4.6049x; 1.0162x over previous
//
#include <hip/hip_runtime.h>
#include <hip/hip_bf16.h>
#include <math.h>

#define BSZ 8
#define SEQL 1024
#define DM 512
#define DI 1024
#define DST 16
#define DTR 32
#define NLAYERS 4
#define ALPHA_C 0.2f
#define LNEPS 1e-5f
#define CH 64          // scan LDS chunk length (t-steps)
#define KSPLIT 2       // split-K factor for the skinny N=64 GEMM
#define YSTR 18        // yb row stride (dwords): 18n mod 32 all-distinct, 8B-aligned

typedef __attribute__((ext_vector_type(8))) short short8;
typedef __attribute__((ext_vector_type(4))) float f32x4;

// async global->LDS, 16B per lane. LDS dest = wave-uniform base + lane*16.
__device__ __forceinline__ void gll16(const void* g, void* l) {
    __builtin_amdgcn_global_load_lds(
        (const __attribute__((address_space(1))) unsigned int*)g,
        (__attribute__((address_space(3))) unsigned int*)l, 16, 0, 0);
}

// DPP row_ror butterfly sum over rows of 16 lanes; result uniform in all 16 lanes
__device__ __forceinline__ float sum16(float x) {
    x += __int_as_float(__builtin_amdgcn_update_dpp(0, __float_as_int(x), 0x121, 0xf, 0xf, true));
    x += __int_as_float(__builtin_amdgcn_update_dpp(0, __float_as_int(x), 0x122, 0xf, 0xf, true));
    x += __int_as_float(__builtin_amdgcn_update_dpp(0, __float_as_int(x), 0x124, 0xf, 0xf, true));
    x += __int_as_float(__builtin_amdgcn_update_dpp(0, __float_as_int(x), 0x128, 0xf, 0xf, true));
    return x;
}

// ---------------- input embedding ----------------
__global__ __launch_bounds__(256) void embed_kernel(const float* __restrict__ x,
                                                    const float* __restrict__ Wi,
                                                    const float* __restrict__ bi,
                                                    float* __restrict__ t) {
    int idx = blockIdx.x * 256 + threadIdx.x;
    if (idx >= BSZ * SEQL * DM) return;
    int d  = idx & (DM - 1);
    int bl = idx >> 9;
    int l  = bl & (SEQL - 1);
    int b  = bl >> 10;
    const float* xb = x + (size_t)b * 3 * SEQL;
    float acc = bi[d];
    acc += xb[0 * SEQL + l] * Wi[0 * DM + d];
    acc += xb[1 * SEQL + l] * Wi[1 * DM + d];
    acc += xb[2 * SEQL + l] * Wi[2 * DM + d];
    t[idx] = acc;
}

// ---------------- layernorm over DM=512, writes bf16 ----------------
__global__ __launch_bounds__(256) void ln_kernel(const float* __restrict__ t,
                                                 const float* __restrict__ w,
                                                 const float* __restrict__ b,
                                                 __hip_bfloat16* __restrict__ xn) {
    int row = blockIdx.x;
    int tid = threadIdx.x;
    const float* r = t + (size_t)row * DM;
    float v0 = r[tid], v1 = r[tid + 256];
    __shared__ float sh[256], sh2[256];
    sh[tid]  = v0 + v1;
    sh2[tid] = v0 * v0 + v1 * v1;
    __syncthreads();
    for (int off = 128; off > 0; off >>= 1) {
        if (tid < off) { sh[tid] += sh[tid + off]; sh2[tid] += sh2[tid + off]; }
        __syncthreads();
    }
    float mu  = sh[0]  * (1.f / DM);
    float var = sh2[0] * (1.f / DM) - mu * mu;
    float rs  = rsqrtf(var + LNEPS);
    xn[(size_t)row * DM + tid]       = __float2bfloat16((v0 - mu) * rs * w[tid]       + b[tid]);
    xn[(size_t)row * DM + tid + 256] = __float2bfloat16((v1 - mu) * rs * w[tid + 256] + b[tid + 256]);
}

// ---------------- transpose + fp32->bf16: W[K][N] -> Wt[N][K], per layer (grid.z) ----------------
__global__ __launch_bounds__(256) void transpose_bf_kernel(const float* __restrict__ W,
                                                           __hip_bfloat16* __restrict__ Wt,
                                                           int K, int N, size_t lstride) {
    const float* Wl = W + (size_t)blockIdx.z * lstride;
    __hip_bfloat16* Wtl = Wt + (size_t)blockIdx.z * lstride;
    __shared__ float tile[32][33];
    int kk = blockIdx.x * 32, nn = blockIdx.y * 32;
    int tx = threadIdx.x & 31, ty = threadIdx.x >> 5;
#pragma unroll
    for (int i = 0; i < 32; i += 8)
        tile[ty + i][tx] = Wl[(size_t)(kk + ty + i) * N + nn + tx];
    __syncthreads();
#pragma unroll
    for (int i = 0; i < 32; i += 8)
        Wtl[(size_t)(nn + ty + i) * K + kk + tx] = __float2bfloat16(tile[tx][ty + i]);
}

// ---------------- bf16 MFMA GEMM: C = A[M,K] @ Bt[N,K]^T + bias (+=C if RES) ----------------
template <bool RES>
__global__ __launch_bounds__(256) void gemm_mfma_kernel(const short* __restrict__ A,
                                                        const short* __restrict__ Bt,
                                                        const float* __restrict__ bias,
                                                        float* __restrict__ C,
                                                        int M, int N, int K) {
    __shared__ __align__(16) short As[128 * 32];
    __shared__ __align__(16) short Bs[128 * 32];
    int tid = threadIdx.x;
    int w = tid >> 6, lane = tid & 63;
    int quad = lane >> 4, ml = lane & 15;
    int wm = w & 1, wn = w >> 1;
    const short* Ab = A + (size_t)blockIdx.x * 128 * K;
    const short* Bb = Bt + (size_t)blockIdx.y * 128 * K;
    f32x4 acc[4][4] = {};
    int s0 = tid, s1 = tid + 256;
    int r0 = s0 >> 2, c0 = (s0 & 3) ^ ((r0 >> 1) & 3);
    int r1 = s1 >> 2, c1 = (s1 & 3) ^ ((r1 >> 1) & 3);
    int aoff[4], boff[4];
#pragma unroll
    for (int t = 0; t < 4; t++) {
        int ra = wm * 64 + t * 16 + ml;
        aoff[t] = ra * 32 + (quad ^ ((ra >> 1) & 3)) * 8;
        int rb = wn * 64 + t * 16 + ml;
        boff[t] = rb * 32 + (quad ^ ((rb >> 1) & 3)) * 8;
    }
    for (int kk = 0; kk < K; kk += 32) {
        gll16(Ab + (size_t)r0 * K + kk + c0 * 8, As + (size_t)(w * 64) * 8);
        gll16(Ab + (size_t)r1 * K + kk + c1 * 8, As + (size_t)(256 + w * 64) * 8);
        gll16(Bb + (size_t)r0 * K + kk + c0 * 8, Bs + (size_t)(w * 64) * 8);
        gll16(Bb + (size_t)r1 * K + kk + c1 * 8, Bs + (size_t)(256 + w * 64) * 8);
        __syncthreads();
        short8 af[4], bfr[4];
#pragma unroll
        for (int t = 0; t < 4; t++) af[t]  = *(const short8*)&As[aoff[t]];
#pragma unroll
        for (int t = 0; t < 4; t++) bfr[t] = *(const short8*)&Bs[boff[t]];
#pragma unroll
        for (int mt = 0; mt < 4; mt++)
#pragma unroll
            for (int nt = 0; nt < 4; nt++)
                acc[mt][nt] = __builtin_amdgcn_mfma_f32_16x16x32_bf16(af[mt], bfr[nt], acc[mt][nt], 0, 0, 0);
        __syncthreads();
    }
#pragma unroll
    for (int mt = 0; mt < 4; mt++) {
#pragma unroll
        for (int nt = 0; nt < 4; nt++) {
            int n = blockIdx.y * 128 + wn * 64 + nt * 16 + ml;
            float bv = bias[n];
#pragma unroll
            for (int r = 0; r < 4; r++) {
                int m = blockIdx.x * 128 + wm * 64 + mt * 16 + quad * 4 + r;
                size_t off = (size_t)m * N + n;
                float v = acc[mt][nt][r] + bv;
                if (RES) v += C[off];
                C[off] = v;
            }
        }
    }
}

// ---------------- causal depthwise conv (D_CONV=4) + SiLU ----------------
__global__ __launch_bounds__(256) void conv_kernel(const float* __restrict__ uz,
                                                   const float* __restrict__ cw,
                                                   const float* __restrict__ cb,
                                                   float* __restrict__ uc) {
    int idx = blockIdx.x * 256 + threadIdx.x;
    int e  = idx & (DI - 1);
    int bl = idx >> 10;
    int l  = bl & (SEQL - 1);
    int b  = bl >> 10;
    const float* u = uz + (size_t)b * SEQL * 2048;
    float acc = cb[e];
#pragma unroll
    for (int k = 0; k < 4; k++) {
        int ll = l - 3 + k;
        float uv = (ll >= 0) ? u[(size_t)ll * 2048 + e] : 0.f;
        acc += uv * cw[e * 4 + k];
    }
    acc = acc / (1.f + expf(-acc));
    uc[idx] = acc;
}

// ---------------- fp32 GEMM 64-wide, split-K: part[ks][M][64] ----------------
__global__ __launch_bounds__(256) void gemm64_splitk_kernel(const float* __restrict__ A,
                                                            const float* __restrict__ Bg,
                                                            float* __restrict__ part,
                                                            int M, int K) {
    __shared__ float As[16][64];
    __shared__ float Bs[16][64];
    const int N = 64;
    int tid = threadIdx.x;
    int tn = tid & 15, tm = tid >> 4;
    int bm = blockIdx.x, ks = blockIdx.y;
    int k0 = ks * (K / KSPLIT), k1 = k0 + K / KSPLIT;
    const float* Ab = A + (size_t)bm * 64 * K;
    float acc[4][4] = {};
    for (int kk = k0; kk < k1; kk += 16) {
#pragma unroll
        for (int i = 0; i < 4; i++) {
            int e = tid + 256 * i;
            int m = e >> 4, k = e & 15;
            As[k][m] = Ab[(size_t)m * K + kk + k];
        }
#pragma unroll
        for (int i = 0; i < 4; i++) {
            int e = tid + 256 * i;
            int k = e >> 6, n = e & 63;
            Bs[k][n] = Bg[(size_t)(kk + k) * N + n];
        }
        __syncthreads();
#pragma unroll
        for (int k = 0; k < 16; k++) {
            float4 a  = *(const float4*)&As[k][tm * 4];
            float4 bv = *(const float4*)&Bs[k][tn * 4];
            float av[4] = {a.x, a.y, a.z, a.w};
            float bw[4] = {bv.x, bv.y, bv.z, bv.w};
#pragma unroll
            for (int i = 0; i < 4; i++)
#pragma unroll
                for (int j = 0; j < 4; j++) acc[i][j] += av[i] * bw[j];
        }
        __syncthreads();
    }
    int m0 = bm * 64 + tm * 4;
    int n0 = tn * 4;
#pragma unroll
    for (int i = 0; i < 4; i++)
#pragma unroll
        for (int j = 0; j < 4; j++)
            part[((size_t)ks * M + m0 + i) * 64 + n0 + j] = acc[i][j];
}

// ---------------- reduce split-K partials; emit dtc[M][32], BC[M][32] interleaved, ssq[M] ----------------
__global__ __launch_bounds__(256) void repack_kernel(const float* __restrict__ part,
                                                     float* __restrict__ dtc,
                                                     float* __restrict__ bc,
                                                     float* __restrict__ ssqb,
                                                     int M) {
    int m = blockIdx.x * 4 + (threadIdx.x >> 6);
    int j = threadIdx.x & 63;
    float v = 0.f;
#pragma unroll
    for (int ks = 0; ks < KSPLIT; ks++) v += part[((size_t)ks * M + m) * 64 + j];
    float s = sum16(v * v);        // row 3 (lanes 48..63) = sum of C^2
    if (j < 32) dtc[(size_t)m * 32 + j] = v;
    else if (j < 48) bc[(size_t)m * 32 + 2 * (j - 32)] = v;          // B_n -> even
    else {
        bc[(size_t)m * 32 + 2 * (j - 48) + 1] = v;                    // C_n -> odd
        if (j == 48) ssqb[m] = s;
    }
}

// ---------------- dt = softplus(dtc @ Wdt + bdt), written into u-half of uz ----------------
__global__ __launch_bounds__(256) void dt_kernel(const float* __restrict__ dtc,
                                                 const float* __restrict__ Wdt,
                                                 const float* __restrict__ bdt,
                                                 float* __restrict__ uzdt) {
    int idx = blockIdx.x * 256 + threadIdx.x;
    int e  = idx & (DI - 1);
    int bl = idx >> 10;
    const float* dr = dtc + (size_t)bl * 32;
    float acc = bdt[e];
#pragma unroll
    for (int r = 0; r < DTR; r++) acc += dr[r] * Wdt[r * DI + e];
    uzdt[(size_t)bl * 2048 + e] = (acc > 20.f) ? acc : log1pf(expf(acc));
}

// ---------------- scan v7: conflict-free LDS, capture epilogue, exp2 ----------------
// Per-t issue: ~16 VALU + 3 ds_read (BC b64, dt b32, u b32). p/u captured via
// cndmask at t%16==n; y/sq/z/silu handled once per 16 t. sZ granule-rotated so
// the lane-varying (ts+n) read is conflict-free; yb rows stride-18.
__device__ __forceinline__ void scan_stage(float* sBC, float* sDT, float* sU, float* sZ, float* sSQ,
                                           const float* __restrict__ ucb,
                                           const float* __restrict__ uzb,
                                           const float* __restrict__ bcp,
                                           const float* __restrict__ sqb,
                                           int e_base, int tid, int tc) {
    int w = tid >> 6;
    int t8 = tid >> 3, c8 = tid & 7;
    gll16(bcp + (size_t)(tc + t8) * 32 + c8 * 4,       sBC + w * 256);
    gll16(bcp + (size_t)(tc + 32 + t8) * 32 + c8 * 4,  sBC + 1024 + w * 256);
    int t4 = tid >> 2, c4 = tid & 3;
    gll16(uzb + (size_t)(tc + t4) * 2048 + e_base + c4 * 4, sDT + w * 256);  // dt
    gll16(ucb + (size_t)(tc + t4) * 1024 + e_base + c4 * 4, sU  + w * 256);  // u
    int c4r = (c4 - (t4 >> 1)) & 3;                                          // rotated granule
    gll16(uzb + (size_t)(tc + t4) * 2048 + 1024 + e_base + c4r * 4, sZ + w * 256);  // z
    if (tid < 16) gll16(sqb + tc + tid * 4, sSQ);
}

__device__ __forceinline__ void scan_flush(const float* yb, __hip_bfloat16* ob,
                                           int e_base, int tcp, int tid) {
#pragma unroll
    for (int r = 0; r < 2; r++) {
        int pid = r * 256 + tid;
        int t = pid >> 3, ep = pid & 7;
        float2 y2 = *(const float2*)&yb[t * YSTR + ep * 2];
        __hip_bfloat162 v;
        v.x = __float2bfloat16(y2.x);
        v.y = __float2bfloat16(y2.y);
        *(__hip_bfloat162*)&ob[(size_t)(tcp + t) * DI + e_base + ep * 2] = v;
    }
}

__global__ __launch_bounds__(256) void scan_kernel(const float* __restrict__ uc,
                                                   const float* __restrict__ uz,     // dt in u-half, z in z-half
                                                   const float* __restrict__ bcb,
                                                   const float* __restrict__ ssqb,
                                                   const float* __restrict__ Alog,
                                                   const float* __restrict__ Dv,
                                                   __hip_bfloat16* __restrict__ out) {
    __shared__ __align__(16) float sBC[2][CH * 32];
    __shared__ __align__(16) float sDT[2][CH * 16];
    __shared__ __align__(16) float sU [2][CH * 16];
    __shared__ __align__(16) float sZ [2][CH * 16];
    __shared__ __align__(16) float sSQ[2][CH];
    __shared__ __align__(16) float yb [2][CH * YSTR];
    int tid = threadIdx.x;
    int g = tid >> 4, n = tid & 15;
    int b = blockIdx.x >> 6;
    int e_base = (blockIdx.x & 63) << 4;
    int e = e_base + g;
    float An2 = -__expf(Alog[e * DST + n]) * 1.4426950408889634f;   // pre-fold log2(e)
    float dv = Dv[e];
    const float* ucb = uc + (size_t)b * SEQL * DI;
    const float* uzb = uz + (size_t)b * SEQL * 2048;
    const float* bcp = bcb + (size_t)b * SEQL * 32;
    const float* sqb = ssqb + (size_t)b * SEQL;
    __hip_bfloat16* ob = out + (size_t)b * SEQL * DI;
    float h = 0.f;
    scan_stage(sBC[0], sDT[0], sU[0], sZ[0], sSQ[0], ucb, uzb, bcp, sqb, e_base, tid, 0);
    int buf = 0;
    for (int c = 0; c < SEQL / CH; c++) {
        int tc = c * CH;
        __syncthreads();   // drains stage(c)'s async loads + prev chunk's yb writes
        if (c + 1 < SEQL / CH)
            scan_stage(sBC[buf ^ 1], sDT[buf ^ 1], sU[buf ^ 1], sZ[buf ^ 1], sSQ[buf ^ 1],
                       ucb, uzb, bcp, sqb, e_base, tid, tc + CH);
        if (c > 0)
            scan_flush(yb[buf ^ 1], ob, e_base, tc - CH, tid);
        const float* pBC = sBC[buf];
        const float* pDT = sDT[buf];
        const float* pU  = sU[buf];
        const float* pZ  = sZ[buf];
        const float* pSQ = sSQ[buf];
        float* pY = yb[buf];
        for (int ts = 0; ts < CH; ts += 16) {
            float pc = 0.f, ucap = 0.f;
#pragma unroll
            for (int j = 0; j < 16; j++) {
                int t = ts + j;
                float2 bcv = *(const float2*)&pBC[t * 32 + n * 2];   // (B_n, C_n)
                float dtv = pDT[t * 16 + g];
                float uv  = pU[t * 16 + g];
                float alC = ALPHA_C * bcv.y;                          // off-chain
                float a = __builtin_amdgcn_exp2f(dtv * An2);
                h = fmaf(a, h, dtv * uv * bcv.x);
                float p = sum16(h * bcv.y);          // uniform over 16 lanes
                h = fmaf(uv - p, alC, h);
                bool cap = (n == j);                 // compile-time j: cmp + 2 cndmask
                pc   = cap ? p  : pc;
                ucap = cap ? uv : ucap;
            }
            int tl = ts + n;
            float sq = pSQ[tl];                                              // conflict-free
            float zv = pZ[tl * 16 + ((((g >> 2) + (tl >> 1)) & 3) << 2) + (g & 3)];  // rotated
            float es2 = ALPHA_C * (ucap - pc);
            float y = fmaf(dv, ucap, fmaf(es2, sq, pc));
            float sz = zv / (1.f + __expf(-zv));
            pY[tl * YSTR + g] = y * sz;
        }
        buf ^= 1;
    }
    __syncthreads();
    scan_flush(yb[buf ^ 1], ob, e_base, SEQL - CH, tid);
}

// ---------------- mean-pool partials ----------------
__global__ __launch_bounds__(512) void pool_kernel(const float* __restrict__ t,
                                                   float* __restrict__ part) {
    int b = blockIdx.x >> 4;
    int c = blockIdx.x & 15;
    int d = threadIdx.x;
    const float* tb = t + ((size_t)b * SEQL + c * 64) * DM + d;
    float s = 0.f;
    for (int l = 0; l < 64; l++) s += tb[(size_t)l * DM];
    part[(size_t)blockIdx.x * DM + d] = s;
}

// ---------------- final: mean, layernorm, classifier ----------------
__global__ __launch_bounds__(512) void final_kernel(const float* __restrict__ part,
                                                    const float* __restrict__ lw,
                                                    const float* __restrict__ lb,
                                                    const float* __restrict__ Wc,
                                                    const float* __restrict__ bc,
                                                    float* __restrict__ out) {
    int b = blockIdx.x;
    int d = threadIdx.x;
    float v = 0.f;
    for (int c = 0; c < 16; c++) v += part[((size_t)b * 16 + c) * DM + d];
    v *= (1.f / SEQL);
    __shared__ float sh[512], sh2[512], nd[512];
    sh[d] = v; sh2[d] = v * v;
    __syncthreads();
    for (int off = 256; off > 0; off >>= 1) {
        if (d < off) { sh[d] += sh[d + off]; sh2[d] += sh2[d + off]; }
        __syncthreads();
    }
    float mu  = sh[0]  * (1.f / DM);
    float var = sh2[0] * (1.f / DM) - mu * mu;
    float rs  = rsqrtf(var + LNEPS);
    nd[d] = (v - mu) * rs * lw[d] + lb[d];
    __syncthreads();
    if (d < 10) {
        float acc = bc[d];
        for (int k = 0; k < DM; k++) acc += nd[k] * Wc[k * 10 + d];
        out[b * 10 + d] = acc;
    }
}

extern "C" void kernel_launch(void* const* d_in, const int* in_sizes, int n_in,
                              void* d_out, int out_size, void* d_ws, size_t ws_size,
                              hipStream_t stream) {
    const float* x      = (const float*)d_in[0];
    const float* W_inp  = (const float*)d_in[1];
    const float* b_inp  = (const float*)d_in[2];
    const float* W_in   = (const float*)d_in[3];
    const float* b_in   = (const float*)d_in[4];
    const float* conv_w = (const float*)d_in[5];
    const float* conv_b = (const float*)d_in[6];
    const float* W_x    = (const float*)d_in[7];
    const float* W_dt   = (const float*)d_in[8];
    const float* b_dt   = (const float*)d_in[9];
    const float* A_log  = (const float*)d_in[10];
    const float* D_skip = (const float*)d_in[11];
    const float* W_out  = (const float*)d_in[12];
    const float* b_out  = (const float*)d_in[13];
    const float* ln_w   = (const float*)d_in[14];
    const float* ln_b   = (const float*)d_in[15];
    const float* lnf_w  = (const float*)d_in[16];
    const float* lnf_b  = (const float*)d_in[17];
    const float* W_cls  = (const float*)d_in[18];
    const float* b_cls  = (const float*)d_in[19];

    const int M = BSZ * SEQL;   // 8192

    float* ws = (float*)d_ws;
    float* t_buf   = ws;                  ws += (size_t)M * DM;
    float* uz      = ws;                  ws += (size_t)M * 2048;
    float* uc      = ws;                  ws += (size_t)M * DI;
    float* dtc     = ws;                  ws += (size_t)M * 32;
    float* bcb     = ws;                  ws += (size_t)M * 32;
    float* ssqb    = ws;                  ws += (size_t)M;
    float* scratch = ws;                  ws += (size_t)M * DI / 2 * 2;
    float* wtin    = ws;                  ws += (size_t)NLAYERS * DM * 2048 / 2;
    float* wtout   = ws;                  ws += (size_t)NLAYERS * DI * DM / 2;
    float* poolp   = ws;                  ws += (size_t)128 * DM;

    __hip_bfloat16* xn_bf = (__hip_bfloat16*)scratch;   // [M][512]
    float*          partb = scratch;                    // [KSPLIT][M][64]
    __hip_bfloat16* uc_bf = (__hip_bfloat16*)scratch;   // [M][1024]
    __hip_bfloat16* wtin_bf  = (__hip_bfloat16*)wtin;   // [L][2048][512]
    __hip_bfloat16* wtout_bf = (__hip_bfloat16*)wtout;  // [L][512][1024]

    embed_kernel<<<(M * DM + 255) / 256, 256, 0, stream>>>(x, W_inp, b_inp, t_buf);
    transpose_bf_kernel<<<dim3(DM / 32, 2048 / 32, NLAYERS), 256, 0, stream>>>(
        W_in, wtin_bf, DM, 2048, (size_t)DM * 2048);
    transpose_bf_kernel<<<dim3(DI / 32, DM / 32, NLAYERS), 256, 0, stream>>>(
        W_out, wtout_bf, DI, DM, (size_t)DI * DM);

    for (int i = 0; i < NLAYERS; i++) {
        ln_kernel<<<M, 256, 0, stream>>>(t_buf, ln_w + i * DM, ln_b + i * DM, xn_bf);
        gemm_mfma_kernel<false><<<dim3(M / 128, 2048 / 128), 256, 0, stream>>>(
            (const short*)xn_bf, (const short*)(wtin_bf + (size_t)i * DM * 2048),
            b_in + i * 2048, uz, M, 2048, DM);
        conv_kernel<<<(M * DI) / 256, 256, 0, stream>>>(
            uz, conv_w + (size_t)i * DI * 4, conv_b + i * DI, uc);
        gemm64_splitk_kernel<<<dim3(M / 64, KSPLIT), 256, 0, stream>>>(
            uc, W_x + (size_t)i * DI * 64, partb, M, DI);
        repack_kernel<<<M / 4, 256, 0, stream>>>(partb, dtc, bcb, ssqb, M);
        dt_kernel<<<(M * DI) / 256, 256, 0, stream>>>(
            dtc, W_dt + (size_t)i * DTR * DI, b_dt + i * DI, uz);
        scan_kernel<<<BSZ * DI / 16, 256, 0, stream>>>(
            uc, uz, bcb, ssqb, A_log + (size_t)i * DI * DST, D_skip + i * DI, uc_bf);
        gemm_mfma_kernel<true><<<dim3(M / 128, DM / 128), 256, 0, stream>>>(
            (const short*)uc_bf, (const short*)(wtout_bf + (size_t)i * DI * DM),
            b_out + i * DM, t_buf, M, DM, DI);
    }

    pool_kernel<<<128, 512, 0, stream>>>(t_buf, poolp);
    final_kernel<<<8, 512, 0, stream>>>(poolp, lnf_w, lnf_b, W_cls, b_cls, (float*)d_out);
}

// Round 7
// 1215.688 us; speedup vs baseline: 5.1761x; 1.1240x over previous
//
#include <hip/hip_runtime.h>
#include <hip/hip_bf16.h>
#include <math.h>

#define BSZ 8
#define SEQL 1024
#define DM 512
#define DI 1024
#define DST 16
#define DTR 32
#define NLAYERS 4
#define ALPHA_C 0.2f
#define LNEPS 1e-5f
#define CH 64          // scan LDS chunk length (t-steps)
#define KS64 8         // split-K for the skinny N=64 MFMA GEMM
#define YSTR 18        // yb row stride (dwords)

typedef __attribute__((ext_vector_type(8))) short short8;
typedef __attribute__((ext_vector_type(4))) float f32x4;

__device__ __forceinline__ void gll16(const void* g, void* l) {
    __builtin_amdgcn_global_load_lds(
        (const __attribute__((address_space(1))) unsigned int*)g,
        (__attribute__((address_space(3))) unsigned int*)l, 16, 0, 0);
}

__device__ __forceinline__ float sum16(float x) {
    x += __int_as_float(__builtin_amdgcn_update_dpp(0, __float_as_int(x), 0x121, 0xf, 0xf, true));
    x += __int_as_float(__builtin_amdgcn_update_dpp(0, __float_as_int(x), 0x122, 0xf, 0xf, true));
    x += __int_as_float(__builtin_amdgcn_update_dpp(0, __float_as_int(x), 0x124, 0xf, 0xf, true));
    x += __int_as_float(__builtin_amdgcn_update_dpp(0, __float_as_int(x), 0x128, 0xf, 0xf, true));
    return x;
}

__device__ __forceinline__ float bf2f(unsigned short v) {
    return __uint_as_float(((unsigned)v) << 16);
}

// ---------------- input embedding ----------------
__global__ __launch_bounds__(256) void embed_kernel(const float* __restrict__ x,
                                                    const float* __restrict__ Wi,
                                                    const float* __restrict__ bi,
                                                    float* __restrict__ t) {
    int idx = blockIdx.x * 256 + threadIdx.x;
    if (idx >= BSZ * SEQL * DM) return;
    int d  = idx & (DM - 1);
    int bl = idx >> 9;
    int l  = bl & (SEQL - 1);
    int b  = bl >> 10;
    const float* xb = x + (size_t)b * 3 * SEQL;
    float acc = bi[d];
    acc += xb[0 * SEQL + l] * Wi[0 * DM + d];
    acc += xb[1 * SEQL + l] * Wi[1 * DM + d];
    acc += xb[2 * SEQL + l] * Wi[2 * DM + d];
    t[idx] = acc;
}

// ---------------- layernorm over DM=512, writes bf16 ----------------
__global__ __launch_bounds__(256) void ln_kernel(const float* __restrict__ t,
                                                 const float* __restrict__ w,
                                                 const float* __restrict__ b,
                                                 __hip_bfloat16* __restrict__ xn) {
    int row = blockIdx.x;
    int tid = threadIdx.x;
    const float* r = t + (size_t)row * DM;
    float v0 = r[tid], v1 = r[tid + 256];
    __shared__ float sh[256], sh2[256];
    sh[tid]  = v0 + v1;
    sh2[tid] = v0 * v0 + v1 * v1;
    __syncthreads();
    for (int off = 128; off > 0; off >>= 1) {
        if (tid < off) { sh[tid] += sh[tid + off]; sh2[tid] += sh2[tid + off]; }
        __syncthreads();
    }
    float mu  = sh[0]  * (1.f / DM);
    float var = sh2[0] * (1.f / DM) - mu * mu;
    float rs  = rsqrtf(var + LNEPS);
    xn[(size_t)row * DM + tid]       = __float2bfloat16((v0 - mu) * rs * w[tid]       + b[tid]);
    xn[(size_t)row * DM + tid + 256] = __float2bfloat16((v1 - mu) * rs * w[tid + 256] + b[tid + 256]);
}

// ---------------- transpose + fp32->bf16: W[K][N] -> Wt[N][K] ----------------
__global__ __launch_bounds__(256) void transpose_bf_kernel(const float* __restrict__ W,
                                                           __hip_bfloat16* __restrict__ Wt,
                                                           int K, int N, size_t lstride) {
    const float* Wl = W + (size_t)blockIdx.z * lstride;
    __hip_bfloat16* Wtl = Wt + (size_t)blockIdx.z * lstride;
    __shared__ float tile[32][33];
    int kk = blockIdx.x * 32, nn = blockIdx.y * 32;
    int tx = threadIdx.x & 31, ty = threadIdx.x >> 5;
#pragma unroll
    for (int i = 0; i < 32; i += 8)
        tile[ty + i][tx] = Wl[(size_t)(kk + ty + i) * N + nn + tx];
    __syncthreads();
#pragma unroll
    for (int i = 0; i < 32; i += 8)
        Wtl[(size_t)(nn + ty + i) * K + kk + tx] = __float2bfloat16(tile[tx][ty + i]);
}

// ---------------- bf16 MFMA GEMM: OUTMODE 0=f32, 1=f32+residual, 2=bf16 ----------------
template <int OUTMODE>
__global__ __launch_bounds__(256) void gemm_mfma_kernel(const short* __restrict__ A,
                                                        const short* __restrict__ Bt,
                                                        const float* __restrict__ bias,
                                                        void* __restrict__ Cv,
                                                        int M, int N, int K) {
    __shared__ __align__(16) short As[128 * 32];
    __shared__ __align__(16) short Bs[128 * 32];
    int tid = threadIdx.x;
    int w = tid >> 6, lane = tid & 63;
    int quad = lane >> 4, ml = lane & 15;
    int wm = w & 1, wn = w >> 1;
    const short* Ab = A + (size_t)blockIdx.x * 128 * K;
    const short* Bb = Bt + (size_t)blockIdx.y * 128 * K;
    f32x4 acc[4][4] = {};
    int s0 = tid, s1 = tid + 256;
    int r0 = s0 >> 2, c0 = (s0 & 3) ^ ((r0 >> 1) & 3);
    int r1 = s1 >> 2, c1 = (s1 & 3) ^ ((r1 >> 1) & 3);
    int aoff[4], boff[4];
#pragma unroll
    for (int t = 0; t < 4; t++) {
        int ra = wm * 64 + t * 16 + ml;
        aoff[t] = ra * 32 + (quad ^ ((ra >> 1) & 3)) * 8;
        int rb = wn * 64 + t * 16 + ml;
        boff[t] = rb * 32 + (quad ^ ((rb >> 1) & 3)) * 8;
    }
    for (int kk = 0; kk < K; kk += 32) {
        gll16(Ab + (size_t)r0 * K + kk + c0 * 8, As + (size_t)(w * 64) * 8);
        gll16(Ab + (size_t)r1 * K + kk + c1 * 8, As + (size_t)(256 + w * 64) * 8);
        gll16(Bb + (size_t)r0 * K + kk + c0 * 8, Bs + (size_t)(w * 64) * 8);
        gll16(Bb + (size_t)r1 * K + kk + c1 * 8, Bs + (size_t)(256 + w * 64) * 8);
        __syncthreads();
        short8 af[4], bfr[4];
#pragma unroll
        for (int t = 0; t < 4; t++) af[t]  = *(const short8*)&As[aoff[t]];
#pragma unroll
        for (int t = 0; t < 4; t++) bfr[t] = *(const short8*)&Bs[boff[t]];
#pragma unroll
        for (int mt = 0; mt < 4; mt++)
#pragma unroll
            for (int nt = 0; nt < 4; nt++)
                acc[mt][nt] = __builtin_amdgcn_mfma_f32_16x16x32_bf16(af[mt], bfr[nt], acc[mt][nt], 0, 0, 0);
        __syncthreads();
    }
#pragma unroll
    for (int mt = 0; mt < 4; mt++) {
#pragma unroll
        for (int nt = 0; nt < 4; nt++) {
            int n = blockIdx.y * 128 + wn * 64 + nt * 16 + ml;
            float bv = bias[n];
#pragma unroll
            for (int r = 0; r < 4; r++) {
                int m = blockIdx.x * 128 + wm * 64 + mt * 16 + quad * 4 + r;
                size_t off = (size_t)m * N + n;
                float v = acc[mt][nt][r] + bv;
                if (OUTMODE == 2) {
                    ((unsigned short*)Cv)[off] = __bfloat16_as_ushort(__float2bfloat16(v));
                } else {
                    float* C = (float*)Cv;
                    if (OUTMODE == 1) v += C[off];
                    C[off] = v;
                }
            }
        }
    }
}

// ---------------- causal depthwise conv (D_CONV=4) + SiLU: bf16 in/out ----------------
__global__ __launch_bounds__(256) void conv_kernel(const unsigned short* __restrict__ uzb,
                                                   const float* __restrict__ cw,
                                                   const float* __restrict__ cb,
                                                   unsigned short* __restrict__ ucb) {
    int idx = blockIdx.x * 256 + threadIdx.x;
    int e  = idx & (DI - 1);
    int bl = idx >> 10;
    int l  = bl & (SEQL - 1);
    int b  = bl >> 10;
    const unsigned short* u = uzb + (size_t)b * SEQL * 2048;
    float acc = cb[e];
#pragma unroll
    for (int k = 0; k < 4; k++) {
        int ll = l - 3 + k;
        float uv = (ll >= 0) ? bf2f(u[(size_t)ll * 2048 + e]) : 0.f;
        acc += uv * cw[e * 4 + k];
    }
    acc = acc / (1.f + __expf(-acc));
    ucb[idx] = __bfloat16_as_ushort(__float2bfloat16(acc));
}

// ---------------- skinny bf16 MFMA GEMM: dbc_part[ks][M][64] = ucb @ Wx^T ----------------
__global__ __launch_bounds__(256) void gemm64_mfma_kernel(const short* __restrict__ A,
                                                          const short* __restrict__ Bt,
                                                          float* __restrict__ part,
                                                          int M) {
    const int K = DI;                  // 1024
    const int Kseg = K / KS64;         // 128
    __shared__ __align__(16) short As[128 * 32];  // 8KB
    __shared__ __align__(16) short Bs[64 * 32];   // 4KB
    int tid = threadIdx.x;
    int w = tid >> 6, lane = tid & 63;
    int quad = lane >> 4, ml = lane & 15;
    int wm = w & 1, wn = w >> 1;
    int bm = blockIdx.x, ks = blockIdx.y;
    const short* Ab = A + (size_t)bm * 128 * K;
    f32x4 acc[4][2] = {};
    int s0 = tid, s1 = tid + 256;
    int r0 = s0 >> 2, c0 = (s0 & 3) ^ ((r0 >> 1) & 3);
    int r1 = s1 >> 2, c1 = (s1 & 3) ^ ((r1 >> 1) & 3);
    int rB = tid >> 2, cB = (tid & 3) ^ ((rB >> 1) & 3);
    int aoff[4], boff[2];
#pragma unroll
    for (int t = 0; t < 4; t++) {
        int ra = wm * 64 + t * 16 + ml;
        aoff[t] = ra * 32 + (quad ^ ((ra >> 1) & 3)) * 8;
    }
#pragma unroll
    for (int t = 0; t < 2; t++) {
        int rb = wn * 32 + t * 16 + ml;
        boff[t] = rb * 32 + (quad ^ ((rb >> 1) & 3)) * 8;
    }
    int k0 = ks * Kseg;
    for (int kk = k0; kk < k0 + Kseg; kk += 32) {
        gll16(Ab + (size_t)r0 * K + kk + c0 * 8, As + (size_t)(w * 64) * 8);
        gll16(Ab + (size_t)r1 * K + kk + c1 * 8, As + (size_t)(256 + w * 64) * 8);
        gll16(Bt + (size_t)rB * K + kk + cB * 8, Bs + (size_t)(w * 64) * 8);
        __syncthreads();
        short8 af[4], bfr[2];
#pragma unroll
        for (int t = 0; t < 4; t++) af[t]  = *(const short8*)&As[aoff[t]];
#pragma unroll
        for (int t = 0; t < 2; t++) bfr[t] = *(const short8*)&Bs[boff[t]];
#pragma unroll
        for (int mt = 0; mt < 4; mt++)
#pragma unroll
            for (int nt = 0; nt < 2; nt++)
                acc[mt][nt] = __builtin_amdgcn_mfma_f32_16x16x32_bf16(af[mt], bfr[nt], acc[mt][nt], 0, 0, 0);
        __syncthreads();
    }
#pragma unroll
    for (int mt = 0; mt < 4; mt++) {
#pragma unroll
        for (int nt = 0; nt < 2; nt++) {
            int n = wn * 32 + nt * 16 + ml;
#pragma unroll
            for (int r = 0; r < 4; r++) {
                int m = bm * 128 + wm * 64 + mt * 16 + quad * 4 + r;
                part[((size_t)ks * M + m) * 64 + n] = acc[mt][nt][r];
            }
        }
    }
}

// ---------------- reduce split-K partials; dtc fp32, bcb bf16-packed, ssq ----------------
__global__ __launch_bounds__(256) void repack_kernel(const float* __restrict__ part,
                                                     float* __restrict__ dtc,
                                                     unsigned* __restrict__ bcb,
                                                     float* __restrict__ ssqb,
                                                     int M) {
    int m = blockIdx.x * 4 + (threadIdx.x >> 6);
    int j = threadIdx.x & 63;
    float v = 0.f;
#pragma unroll
    for (int ks = 0; ks < KS64; ks++) v += part[((size_t)ks * M + m) * 64 + j];
    if (j < 32) {
        dtc[(size_t)m * 32 + j] = v;
    } else {
        int n = (j - 32) & 15;
        unsigned short u16 = __bfloat16_as_ushort(__float2bfloat16(v));
        unsigned short* bp = (unsigned short*)(bcb + (size_t)m * 16 + n);
        if (j < 48) {
            bp[0] = u16;                       // B -> low half
        } else {
            bp[1] = u16;                       // C -> high half
            float vr = bf2f(u16);
            float s = sum16(vr * vr);          // lanes 48..63 = one DPP row
            if (j == 48) ssqb[m] = s;
        }
    }
}

// ---------------- dt: LDS-tiled  dtb = softplus(dtc @ Wdt + bdt) ----------------
__global__ __launch_bounds__(256) void dt_kernel(const float* __restrict__ dtc,
                                                 const float* __restrict__ Wdt,
                                                 const float* __restrict__ bdt,
                                                 float* __restrict__ dtb) {
    __shared__ float sdtc[32][32];
    __shared__ float swdt[32][256];
    int tid = threadIdx.x;
    int e0 = (blockIdx.x & 3) * 256;
    int m0 = (blockIdx.x >> 2) * 32;
#pragma unroll
    for (int i = 0; i < 4; i++) {
        int idx = tid + 256 * i;
        sdtc[idx >> 5][idx & 31] = dtc[(size_t)(m0 + (idx >> 5)) * 32 + (idx & 31)];
    }
#pragma unroll
    for (int r = 0; r < 32; r++) swdt[r][tid] = Wdt[(size_t)r * DI + e0 + tid];
    __syncthreads();
    float wc[32];
#pragma unroll
    for (int r = 0; r < 32; r++) wc[r] = swdt[r][tid];
    float bv = bdt[e0 + tid];
    for (int m = 0; m < 32; m++) {
        float acc = bv;
#pragma unroll
        for (int r4 = 0; r4 < 8; r4++) {
            float4 d4 = *(const float4*)&sdtc[m][r4 * 4];
            acc = fmaf(d4.x, wc[r4 * 4 + 0], acc);
            acc = fmaf(d4.y, wc[r4 * 4 + 1], acc);
            acc = fmaf(d4.z, wc[r4 * 4 + 2], acc);
            acc = fmaf(d4.w, wc[r4 * 4 + 3], acc);
        }
        float sp = (acc > 20.f) ? acc : log1pf(__expf(acc));
        dtb[(size_t)(m0 + m) * DI + e0 + tid] = sp;
    }
}

// ---------------- scan v8: bf16 u/z/BC staging, capture epilogue ----------------
__device__ __forceinline__ void scan_stage(unsigned* sBC, float* sDT, unsigned short* sU,
                                           unsigned short* sZ, float* sSQ,
                                           const unsigned short* __restrict__ ucb_row,
                                           const float* __restrict__ dtb_row,
                                           const unsigned short* __restrict__ uzb_row,
                                           const unsigned* __restrict__ bcb_row,
                                           const float* __restrict__ sqb,
                                           int e_base, int tid, int tc) {
    int w = tid >> 6;
    // BC: [64 t][16 n] dwords = 4KB
    gll16(bcb_row + (size_t)(tc + (tid >> 2)) * 16 + (tid & 3) * 4, sBC + w * 256);
    // dt: [64 t][16 e] fp32 = 4KB
    gll16(dtb_row + (size_t)(tc + (tid >> 2)) * 1024 + e_base + (tid & 3) * 4, sDT + w * 256);
    if (w < 2) {
        int t = tid >> 1, half = tid & 1;     // u: [64 t][16 e] bf16 = 2KB
        gll16(ucb_row + (size_t)(tc + t) * 1024 + e_base + half * 8, sU + w * 512);
        if (tid < 16) gll16(sqb + tc + tid * 4, sSQ);
    } else {
        int j = tid - 128;
        int t = j >> 1, half = j & 1;         // z: bf16 = 2KB
        gll16(uzb_row + (size_t)(tc + t) * 2048 + 1024 + e_base + half * 8, sZ + (w - 2) * 512);
    }
}

__device__ __forceinline__ void scan_flush(const float* yb, __hip_bfloat16* ob,
                                           int e_base, int tcp, int tid) {
#pragma unroll
    for (int r = 0; r < 2; r++) {
        int pid = r * 256 + tid;
        int t = pid >> 3, ep = pid & 7;
        float2 y2 = *(const float2*)&yb[t * YSTR + ep * 2];
        __hip_bfloat162 v;
        v.x = __float2bfloat16(y2.x);
        v.y = __float2bfloat16(y2.y);
        *(__hip_bfloat162*)&ob[(size_t)(tcp + t) * DI + e_base + ep * 2] = v;
    }
}

__global__ __launch_bounds__(256) void scan_kernel(const unsigned short* __restrict__ ucb,
                                                   const float* __restrict__ dtb,
                                                   const unsigned short* __restrict__ uzb,
                                                   const unsigned* __restrict__ bcb,
                                                   const float* __restrict__ ssqb,
                                                   const float* __restrict__ Alog,
                                                   const float* __restrict__ Dv,
                                                   __hip_bfloat16* __restrict__ out) {
    __shared__ __align__(16) unsigned       sBC[2][CH * 16];
    __shared__ __align__(16) float          sDT[2][CH * 16];
    __shared__ __align__(16) unsigned short sU [2][CH * 16];
    __shared__ __align__(16) unsigned short sZ [2][CH * 16];
    __shared__ __align__(16) float          sSQ[2][CH];
    __shared__ __align__(16) float          yb [2][CH * YSTR];
    int tid = threadIdx.x;
    int g = tid >> 4, n = tid & 15;
    int b = blockIdx.x >> 6;
    int e_base = (blockIdx.x & 63) << 4;
    int e = e_base + g;
    float An2 = -__expf(Alog[e * DST + n]) * 1.4426950408889634f;
    float dv = Dv[e];
    const unsigned short* ucb_row = ucb + (size_t)b * SEQL * DI;
    const float*          dtb_row = dtb + (size_t)b * SEQL * DI;
    const unsigned short* uzb_row = uzb + (size_t)b * SEQL * 2048;
    const unsigned*       bcb_row = bcb + (size_t)b * SEQL * 16;
    const float*          sqb     = ssqb + (size_t)b * SEQL;
    __hip_bfloat16* ob = out + (size_t)b * SEQL * DI;
    float h = 0.f;
    scan_stage(sBC[0], sDT[0], sU[0], sZ[0], sSQ[0], ucb_row, dtb_row, uzb_row, bcb_row, sqb, e_base, tid, 0);
    int buf = 0;
    for (int c = 0; c < SEQL / CH; c++) {
        int tc = c * CH;
        __syncthreads();
        if (c + 1 < SEQL / CH)
            scan_stage(sBC[buf ^ 1], sDT[buf ^ 1], sU[buf ^ 1], sZ[buf ^ 1], sSQ[buf ^ 1],
                       ucb_row, dtb_row, uzb_row, bcb_row, sqb, e_base, tid, tc + CH);
        if (c > 0)
            scan_flush(yb[buf ^ 1], ob, e_base, tc - CH, tid);
        const unsigned* pBC = sBC[buf];
        const float* pDT = sDT[buf];
        const unsigned short* pU = sU[buf];
        const unsigned short* pZ = sZ[buf];
        const float* pSQ = sSQ[buf];
        float* pY = yb[buf];
        for (int ts = 0; ts < CH; ts += 16) {
            float pc = 0.f, ucap = 0.f;
#pragma unroll
            for (int j = 0; j < 16; j++) {
                int t = ts + j;
                unsigned bcd = pBC[t * 16 + n];
                float Bn = __uint_as_float(bcd << 16);
                float Cn = __uint_as_float(bcd & 0xFFFF0000u);
                float dtv = pDT[t * 16 + g];
                float uv  = bf2f(pU[t * 16 + g]);
                float alC = ALPHA_C * Cn;
                float a = __builtin_amdgcn_exp2f(dtv * An2);
                h = fmaf(a, h, dtv * uv * Bn);
                float p = sum16(h * Cn);
                h = fmaf(uv - p, alC, h);
                bool cap = (n == j);
                pc   = cap ? p  : pc;
                ucap = cap ? uv : ucap;
            }
            int tl = ts + n;
            float sq = pSQ[tl];
            float zv = bf2f(pZ[tl * 16 + g]);
            float es2 = ALPHA_C * (ucap - pc);
            float y = fmaf(dv, ucap, fmaf(es2, sq, pc));
            float sz = zv / (1.f + __expf(-zv));
            pY[tl * YSTR + g] = y * sz;
        }
        buf ^= 1;
    }
    __syncthreads();
    scan_flush(yb[buf ^ 1], ob, e_base, SEQL - CH, tid);
}

// ---------------- mean-pool partials ----------------
__global__ __launch_bounds__(512) void pool_kernel(const float* __restrict__ t,
                                                   float* __restrict__ part) {
    int b = blockIdx.x >> 4;
    int c = blockIdx.x & 15;
    int d = threadIdx.x;
    const float* tb = t + ((size_t)b * SEQL + c * 64) * DM + d;
    float s = 0.f;
    for (int l = 0; l < 64; l++) s += tb[(size_t)l * DM];
    part[(size_t)blockIdx.x * DM + d] = s;
}

// ---------------- final: mean, layernorm, classifier ----------------
__global__ __launch_bounds__(512) void final_kernel(const float* __restrict__ part,
                                                    const float* __restrict__ lw,
                                                    const float* __restrict__ lb,
                                                    const float* __restrict__ Wc,
                                                    const float* __restrict__ bc,
                                                    float* __restrict__ out) {
    int b = blockIdx.x;
    int d = threadIdx.x;
    float v = 0.f;
    for (int c = 0; c < 16; c++) v += part[((size_t)b * 16 + c) * DM + d];
    v *= (1.f / SEQL);
    __shared__ float sh[512], sh2[512], nd[512];
    sh[d] = v; sh2[d] = v * v;
    __syncthreads();
    for (int off = 256; off > 0; off >>= 1) {
        if (d < off) { sh[d] += sh[d + off]; sh2[d] += sh2[d + off]; }
        __syncthreads();
    }
    float mu  = sh[0]  * (1.f / DM);
    float var = sh2[0] * (1.f / DM) - mu * mu;
    float rs  = rsqrtf(var + LNEPS);
    nd[d] = (v - mu) * rs * lw[d] + lb[d];
    __syncthreads();
    if (d < 10) {
        float acc = bc[d];
        for (int k = 0; k < DM; k++) acc += nd[k] * Wc[k * 10 + d];
        out[b * 10 + d] = acc;
    }
}

extern "C" void kernel_launch(void* const* d_in, const int* in_sizes, int n_in,
                              void* d_out, int out_size, void* d_ws, size_t ws_size,
                              hipStream_t stream) {
    const float* x      = (const float*)d_in[0];
    const float* W_inp  = (const float*)d_in[1];
    const float* b_inp  = (const float*)d_in[2];
    const float* W_in   = (const float*)d_in[3];
    const float* b_in   = (const float*)d_in[4];
    const float* conv_w = (const float*)d_in[5];
    const float* conv_b = (const float*)d_in[6];
    const float* W_x    = (const float*)d_in[7];
    const float* W_dt   = (const float*)d_in[8];
    const float* b_dt   = (const float*)d_in[9];
    const float* A_log  = (const float*)d_in[10];
    const float* D_skip = (const float*)d_in[11];
    const float* W_out  = (const float*)d_in[12];
    const float* b_out  = (const float*)d_in[13];
    const float* ln_w   = (const float*)d_in[14];
    const float* ln_b   = (const float*)d_in[15];
    const float* lnf_w  = (const float*)d_in[16];
    const float* lnf_b  = (const float*)d_in[17];
    const float* W_cls  = (const float*)d_in[18];
    const float* b_cls  = (const float*)d_in[19];

    const int M = BSZ * SEQL;   // 8192

    float* ws = (float*)d_ws;
    float* t_buf = ws;                    ws += (size_t)M * DM;            // fp32
    unsigned short* uzb = (unsigned short*)ws;  ws += (size_t)M * 2048 / 2; // bf16 [M][2048]
    unsigned short* ucb = (unsigned short*)ws;  ws += (size_t)M * DI / 2;   // bf16 [M][1024]
    float* dtb   = ws;                    ws += (size_t)M * DI;            // fp32 [M][1024]
    float* dtc   = ws;                    ws += (size_t)M * 32;
    unsigned* bcbu = (unsigned*)ws;       ws += (size_t)M * 16;            // packed bf16 (B,C)
    float* ssqb  = ws;                    ws += (size_t)M;
    unsigned short* xn_bf = (unsigned short*)ws;  ws += (size_t)M * DM / 2; // bf16 [M][512]
    unsigned short* ucs_bf = (unsigned short*)ws; ws += (size_t)M * DI / 2; // bf16 scan out
    float* partb = ws;                    ws += (size_t)KS64 * M * 64;
    unsigned short* wtin_bf  = (unsigned short*)ws; ws += (size_t)NLAYERS * DM * 2048 / 2;
    unsigned short* wtout_bf = (unsigned short*)ws; ws += (size_t)NLAYERS * DI * DM / 2;
    unsigned short* wxt_bf   = (unsigned short*)ws; ws += (size_t)NLAYERS * DI * 64 / 2 + 64;
    float* poolp = ws;                    ws += (size_t)128 * DM;

    embed_kernel<<<(M * DM + 255) / 256, 256, 0, stream>>>(x, W_inp, b_inp, t_buf);
    transpose_bf_kernel<<<dim3(DM / 32, 2048 / 32, NLAYERS), 256, 0, stream>>>(
        W_in, (__hip_bfloat16*)wtin_bf, DM, 2048, (size_t)DM * 2048);
    transpose_bf_kernel<<<dim3(DI / 32, DM / 32, NLAYERS), 256, 0, stream>>>(
        W_out, (__hip_bfloat16*)wtout_bf, DI, DM, (size_t)DI * DM);
    transpose_bf_kernel<<<dim3(DI / 32, 64 / 32, NLAYERS), 256, 0, stream>>>(
        W_x, (__hip_bfloat16*)wxt_bf, DI, 64, (size_t)DI * 64);

    for (int i = 0; i < NLAYERS; i++) {
        ln_kernel<<<M, 256, 0, stream>>>(t_buf, ln_w + i * DM, ln_b + i * DM,
                                         (__hip_bfloat16*)xn_bf);
        gemm_mfma_kernel<2><<<dim3(M / 128, 2048 / 128), 256, 0, stream>>>(
            (const short*)xn_bf, (const short*)(wtin_bf + (size_t)i * DM * 2048),
            b_in + i * 2048, uzb, M, 2048, DM);
        conv_kernel<<<(M * DI) / 256, 256, 0, stream>>>(
            uzb, conv_w + (size_t)i * DI * 4, conv_b + i * DI, ucb);
        gemm64_mfma_kernel<<<dim3(M / 128, KS64), 256, 0, stream>>>(
            (const short*)ucb, (const short*)(wxt_bf + (size_t)i * DI * 64), partb, M);
        repack_kernel<<<M / 4, 256, 0, stream>>>(partb, dtc, bcbu, ssqb, M);
        dt_kernel<<<(M / 32) * 4, 256, 0, stream>>>(
            dtc, W_dt + (size_t)i * DTR * DI, b_dt + i * DI, dtb);
        scan_kernel<<<BSZ * DI / 16, 256, 0, stream>>>(
            ucb, dtb, uzb, bcbu, ssqb, A_log + (size_t)i * DI * DST, D_skip + i * DI,
            (__hip_bfloat16*)ucs_bf);
        gemm_mfma_kernel<1><<<dim3(M / 128, DM / 128), 256, 0, stream>>>(
            (const short*)ucs_bf, (const short*)(wtout_bf + (size_t)i * DI * DM),
            b_out + i * DM, t_buf, M, DM, DI);
    }

    pool_kernel<<<128, 512, 0, stream>>>(t_buf, poolp);
    final_kernel<<<8, 512, 0, stream>>>(poolp, lnf_w, lnf_b, W_cls, b_cls, (float*)d_out);
}

// Round 8
// 1163.559 us; speedup vs baseline: 5.4080x; 1.0448x over previous
//
#include <hip/hip_runtime.h>
#include <hip/hip_bf16.h>
#include <math.h>

#define BSZ 8
#define SEQL 1024
#define DM 512
#define DI 1024
#define DST 16
#define DTR 32
#define NLAYERS 4
#define ALPHA_C 0.2f
#define LNEPS 1e-5f
#define CH 64          // scan LDS chunk length (t-steps)
#define KS64 8         // split-K for the skinny N=64 MFMA GEMM
#define YSTR 18        // yb row stride (dwords)

typedef __attribute__((ext_vector_type(8))) short short8;
typedef __attribute__((ext_vector_type(4))) float f32x4;

__device__ __forceinline__ void gll16(const void* g, void* l) {
    __builtin_amdgcn_global_load_lds(
        (const __attribute__((address_space(1))) unsigned int*)g,
        (__attribute__((address_space(3))) unsigned int*)l, 16, 0, 0);
}

__device__ __forceinline__ float sum16(float x) {
    x += __int_as_float(__builtin_amdgcn_update_dpp(0, __float_as_int(x), 0x121, 0xf, 0xf, true));
    x += __int_as_float(__builtin_amdgcn_update_dpp(0, __float_as_int(x), 0x122, 0xf, 0xf, true));
    x += __int_as_float(__builtin_amdgcn_update_dpp(0, __float_as_int(x), 0x124, 0xf, 0xf, true));
    x += __int_as_float(__builtin_amdgcn_update_dpp(0, __float_as_int(x), 0x128, 0xf, 0xf, true));
    return x;
}

__device__ __forceinline__ float bf2f(unsigned short v) {
    return __uint_as_float(((unsigned)v) << 16);
}

// ---------------- input embedding ----------------
__global__ __launch_bounds__(256) void embed_kernel(const float* __restrict__ x,
                                                    const float* __restrict__ Wi,
                                                    const float* __restrict__ bi,
                                                    float* __restrict__ t) {
    int idx = blockIdx.x * 256 + threadIdx.x;
    if (idx >= BSZ * SEQL * DM) return;
    int d  = idx & (DM - 1);
    int bl = idx >> 9;
    int l  = bl & (SEQL - 1);
    int b  = bl >> 10;
    const float* xb = x + (size_t)b * 3 * SEQL;
    float acc = bi[d];
    acc += xb[0 * SEQL + l] * Wi[0 * DM + d];
    acc += xb[1 * SEQL + l] * Wi[1 * DM + d];
    acc += xb[2 * SEQL + l] * Wi[2 * DM + d];
    t[idx] = acc;
}

// ---------------- layernorm over DM=512, writes bf16 ----------------
__global__ __launch_bounds__(256) void ln_kernel(const float* __restrict__ t,
                                                 const float* __restrict__ w,
                                                 const float* __restrict__ b,
                                                 __hip_bfloat16* __restrict__ xn) {
    int row = blockIdx.x;
    int tid = threadIdx.x;
    const float* r = t + (size_t)row * DM;
    float v0 = r[tid], v1 = r[tid + 256];
    __shared__ float sh[256], sh2[256];
    sh[tid]  = v0 + v1;
    sh2[tid] = v0 * v0 + v1 * v1;
    __syncthreads();
    for (int off = 128; off > 0; off >>= 1) {
        if (tid < off) { sh[tid] += sh[tid + off]; sh2[tid] += sh2[tid + off]; }
        __syncthreads();
    }
    float mu  = sh[0]  * (1.f / DM);
    float var = sh2[0] * (1.f / DM) - mu * mu;
    float rs  = rsqrtf(var + LNEPS);
    xn[(size_t)row * DM + tid]       = __float2bfloat16((v0 - mu) * rs * w[tid]       + b[tid]);
    xn[(size_t)row * DM + tid + 256] = __float2bfloat16((v1 - mu) * rs * w[tid + 256] + b[tid + 256]);
}

// ---------------- transpose + fp32->bf16: W[K][N] -> Wt[N][K] ----------------
__global__ __launch_bounds__(256) void transpose_bf_kernel(const float* __restrict__ W,
                                                           __hip_bfloat16* __restrict__ Wt,
                                                           int K, int N, size_t lstride) {
    const float* Wl = W + (size_t)blockIdx.z * lstride;
    __hip_bfloat16* Wtl = Wt + (size_t)blockIdx.z * lstride;
    __shared__ float tile[32][33];
    int kk = blockIdx.x * 32, nn = blockIdx.y * 32;
    int tx = threadIdx.x & 31, ty = threadIdx.x >> 5;
#pragma unroll
    for (int i = 0; i < 32; i += 8)
        tile[ty + i][tx] = Wl[(size_t)(kk + ty + i) * N + nn + tx];
    __syncthreads();
#pragma unroll
    for (int i = 0; i < 32; i += 8)
        Wtl[(size_t)(nn + ty + i) * K + kk + tx] = __float2bfloat16(tile[tx][ty + i]);
}

// ---------------- bf16 MFMA GEMM 128x128: OUTMODE 0=f32, 1=f32+res, 2=bf16 ----------------
template <int OUTMODE>
__global__ __launch_bounds__(256) void gemm_mfma_kernel(const short* __restrict__ A,
                                                        const short* __restrict__ Bt,
                                                        const float* __restrict__ bias,
                                                        void* __restrict__ Cv,
                                                        int M, int N, int K) {
    __shared__ __align__(16) short As[128 * 32];
    __shared__ __align__(16) short Bs[128 * 32];
    int tid = threadIdx.x;
    int w = tid >> 6, lane = tid & 63;
    int quad = lane >> 4, ml = lane & 15;
    int wm = w & 1, wn = w >> 1;
    const short* Ab = A + (size_t)blockIdx.x * 128 * K;
    const short* Bb = Bt + (size_t)blockIdx.y * 128 * K;
    f32x4 acc[4][4] = {};
    int s0 = tid, s1 = tid + 256;
    int r0 = s0 >> 2, c0 = (s0 & 3) ^ ((r0 >> 1) & 3);
    int r1 = s1 >> 2, c1 = (s1 & 3) ^ ((r1 >> 1) & 3);
    int aoff[4], boff[4];
#pragma unroll
    for (int t = 0; t < 4; t++) {
        int ra = wm * 64 + t * 16 + ml;
        aoff[t] = ra * 32 + (quad ^ ((ra >> 1) & 3)) * 8;
        int rb = wn * 64 + t * 16 + ml;
        boff[t] = rb * 32 + (quad ^ ((rb >> 1) & 3)) * 8;
    }
    for (int kk = 0; kk < K; kk += 32) {
        gll16(Ab + (size_t)r0 * K + kk + c0 * 8, As + (size_t)(w * 64) * 8);
        gll16(Ab + (size_t)r1 * K + kk + c1 * 8, As + (size_t)(256 + w * 64) * 8);
        gll16(Bb + (size_t)r0 * K + kk + c0 * 8, Bs + (size_t)(w * 64) * 8);
        gll16(Bb + (size_t)r1 * K + kk + c1 * 8, Bs + (size_t)(256 + w * 64) * 8);
        __syncthreads();
        short8 af[4], bfr[4];
#pragma unroll
        for (int t = 0; t < 4; t++) af[t]  = *(const short8*)&As[aoff[t]];
#pragma unroll
        for (int t = 0; t < 4; t++) bfr[t] = *(const short8*)&Bs[boff[t]];
#pragma unroll
        for (int mt = 0; mt < 4; mt++)
#pragma unroll
            for (int nt = 0; nt < 4; nt++)
                acc[mt][nt] = __builtin_amdgcn_mfma_f32_16x16x32_bf16(af[mt], bfr[nt], acc[mt][nt], 0, 0, 0);
        __syncthreads();
    }
#pragma unroll
    for (int mt = 0; mt < 4; mt++) {
#pragma unroll
        for (int nt = 0; nt < 4; nt++) {
            int n = blockIdx.y * 128 + wn * 64 + nt * 16 + ml;
            float bv = bias[n];
#pragma unroll
            for (int r = 0; r < 4; r++) {
                int m = blockIdx.x * 128 + wm * 64 + mt * 16 + quad * 4 + r;
                size_t off = (size_t)m * N + n;
                float v = acc[mt][nt][r] + bv;
                if (OUTMODE == 2) {
                    ((unsigned short*)Cv)[off] = __bfloat16_as_ushort(__float2bfloat16(v));
                } else {
                    float* C = (float*)Cv;
                    if (OUTMODE == 1) v += C[off];
                    C[off] = v;
                }
            }
        }
    }
}

// ---------------- bf16 MFMA GEMM 64x64 + bias + residual (for N=512 out-proj) ----------------
__global__ __launch_bounds__(256) void gemm6464_res_kernel(const short* __restrict__ A,
                                                           const short* __restrict__ Bt,
                                                           const float* __restrict__ bias,
                                                           float* __restrict__ C,
                                                           int M, int N, int K) {
    __shared__ __align__(16) short As[64 * 32];
    __shared__ __align__(16) short Bs[64 * 32];
    int tid = threadIdx.x;
    int w = tid >> 6, lane = tid & 63;
    int quad = lane >> 4, ml = lane & 15;
    int wm = w & 1, wn = w >> 1;
    const short* Ab = A + (size_t)blockIdx.x * 64 * K;
    const short* Bb = Bt + (size_t)blockIdx.y * 64 * K;
    f32x4 acc[2][2] = {};
    int r0 = tid >> 2, c0 = (tid & 3) ^ ((r0 >> 1) & 3);
    int aoff[2], boff[2];
#pragma unroll
    for (int t = 0; t < 2; t++) {
        int ra = wm * 32 + t * 16 + ml;
        aoff[t] = ra * 32 + (quad ^ ((ra >> 1) & 3)) * 8;
        int rb = wn * 32 + t * 16 + ml;
        boff[t] = rb * 32 + (quad ^ ((rb >> 1) & 3)) * 8;
    }
    for (int kk = 0; kk < K; kk += 32) {
        gll16(Ab + (size_t)r0 * K + kk + c0 * 8, As + (size_t)(w * 64) * 8);
        gll16(Bb + (size_t)r0 * K + kk + c0 * 8, Bs + (size_t)(w * 64) * 8);
        __syncthreads();
        short8 af[2], bfr[2];
#pragma unroll
        for (int t = 0; t < 2; t++) af[t]  = *(const short8*)&As[aoff[t]];
#pragma unroll
        for (int t = 0; t < 2; t++) bfr[t] = *(const short8*)&Bs[boff[t]];
#pragma unroll
        for (int mt = 0; mt < 2; mt++)
#pragma unroll
            for (int nt = 0; nt < 2; nt++)
                acc[mt][nt] = __builtin_amdgcn_mfma_f32_16x16x32_bf16(af[mt], bfr[nt], acc[mt][nt], 0, 0, 0);
        __syncthreads();
    }
#pragma unroll
    for (int mt = 0; mt < 2; mt++) {
#pragma unroll
        for (int nt = 0; nt < 2; nt++) {
            int n = blockIdx.y * 64 + wn * 32 + nt * 16 + ml;
            float bv = bias[n];
#pragma unroll
            for (int r = 0; r < 4; r++) {
                int m = blockIdx.x * 64 + wm * 32 + mt * 16 + quad * 4 + r;
                size_t off = (size_t)m * N + n;
                C[off] = acc[mt][nt][r] + bv + C[off];
            }
        }
    }
}

// ---------------- causal depthwise conv (D_CONV=4) + SiLU: bf16 in/out ----------------
__global__ __launch_bounds__(256) void conv_kernel(const unsigned short* __restrict__ uzb,
                                                   const float* __restrict__ cw,
                                                   const float* __restrict__ cb,
                                                   unsigned short* __restrict__ ucb) {
    int idx = blockIdx.x * 256 + threadIdx.x;
    int e  = idx & (DI - 1);
    int bl = idx >> 10;
    int l  = bl & (SEQL - 1);
    int b  = bl >> 10;
    const unsigned short* u = uzb + (size_t)b * SEQL * 2048;
    float acc = cb[e];
#pragma unroll
    for (int k = 0; k < 4; k++) {
        int ll = l - 3 + k;
        float uv = (ll >= 0) ? bf2f(u[(size_t)ll * 2048 + e]) : 0.f;
        acc += uv * cw[e * 4 + k];
    }
    acc = acc / (1.f + __expf(-acc));
    ucb[idx] = __bfloat16_as_ushort(__float2bfloat16(acc));
}

// ---------------- skinny bf16 MFMA GEMM: dbc_part[ks][M][64] = ucb @ Wx^T ----------------
__global__ __launch_bounds__(256) void gemm64_mfma_kernel(const short* __restrict__ A,
                                                          const short* __restrict__ Bt,
                                                          float* __restrict__ part,
                                                          int M) {
    const int K = DI;
    const int Kseg = K / KS64;
    __shared__ __align__(16) short As[128 * 32];
    __shared__ __align__(16) short Bs[64 * 32];
    int tid = threadIdx.x;
    int w = tid >> 6, lane = tid & 63;
    int quad = lane >> 4, ml = lane & 15;
    int wm = w & 1, wn = w >> 1;
    int bm = blockIdx.x, ks = blockIdx.y;
    const short* Ab = A + (size_t)bm * 128 * K;
    f32x4 acc[4][2] = {};
    int s0 = tid, s1 = tid + 256;
    int r0 = s0 >> 2, c0 = (s0 & 3) ^ ((r0 >> 1) & 3);
    int r1 = s1 >> 2, c1 = (s1 & 3) ^ ((r1 >> 1) & 3);
    int rB = tid >> 2, cB = (tid & 3) ^ ((rB >> 1) & 3);
    int aoff[4], boff[2];
#pragma unroll
    for (int t = 0; t < 4; t++) {
        int ra = wm * 64 + t * 16 + ml;
        aoff[t] = ra * 32 + (quad ^ ((ra >> 1) & 3)) * 8;
    }
#pragma unroll
    for (int t = 0; t < 2; t++) {
        int rb = wn * 32 + t * 16 + ml;
        boff[t] = rb * 32 + (quad ^ ((rb >> 1) & 3)) * 8;
    }
    int k0 = ks * Kseg;
    for (int kk = k0; kk < k0 + Kseg; kk += 32) {
        gll16(Ab + (size_t)r0 * K + kk + c0 * 8, As + (size_t)(w * 64) * 8);
        gll16(Ab + (size_t)r1 * K + kk + c1 * 8, As + (size_t)(256 + w * 64) * 8);
        gll16(Bt + (size_t)rB * K + kk + cB * 8, Bs + (size_t)(w * 64) * 8);
        __syncthreads();
        short8 af[4], bfr[2];
#pragma unroll
        for (int t = 0; t < 4; t++) af[t]  = *(const short8*)&As[aoff[t]];
#pragma unroll
        for (int t = 0; t < 2; t++) bfr[t] = *(const short8*)&Bs[boff[t]];
#pragma unroll
        for (int mt = 0; mt < 4; mt++)
#pragma unroll
            for (int nt = 0; nt < 2; nt++)
                acc[mt][nt] = __builtin_amdgcn_mfma_f32_16x16x32_bf16(af[mt], bfr[nt], acc[mt][nt], 0, 0, 0);
        __syncthreads();
    }
#pragma unroll
    for (int mt = 0; mt < 4; mt++) {
#pragma unroll
        for (int nt = 0; nt < 2; nt++) {
            int n = wn * 32 + nt * 16 + ml;
#pragma unroll
            for (int r = 0; r < 4; r++) {
                int m = bm * 128 + wm * 64 + mt * 16 + quad * 4 + r;
                part[((size_t)ks * M + m) * 64 + n] = acc[mt][nt][r];
            }
        }
    }
}

// ---------------- reduce split-K partials (B,C only): bcb bf16-packed, ssq ----------------
// 256 threads = 8 m x 32 j (j indexes cols 32..63)
__global__ __launch_bounds__(256) void repack_kernel(const float* __restrict__ part,
                                                     unsigned* __restrict__ bcb,
                                                     float* __restrict__ ssqb,
                                                     int M) {
    int m = blockIdx.x * 8 + (threadIdx.x >> 5);
    int j = threadIdx.x & 31;
    float v = 0.f;
#pragma unroll
    for (int ks = 0; ks < KS64; ks++) v += part[((size_t)ks * M + m) * 64 + 32 + j];
    int n = j & 15;
    unsigned short u16 = __bfloat16_as_ushort(__float2bfloat16(v));
    unsigned short* bp = (unsigned short*)(bcb + (size_t)m * 16 + n);
    if (j < 16) {
        bp[0] = u16;                       // B -> low half
    } else {
        bp[1] = u16;                       // C -> high half
        float vr = bf2f(u16);
        float s = sum16(vr * vr);          // lanes 16..31 / 48..63 = aligned DPP rows
        if (j == 16) ssqb[m] = s;
    }
}

// ---------------- dt: re-reduce partb, softplus, pack (dt|u) dwords ----------------
__global__ __launch_bounds__(256) void dt_kernel(const float* __restrict__ part,
                                                 const float* __restrict__ Wdt,
                                                 const float* __restrict__ bdt,
                                                 const unsigned short* __restrict__ ucb,
                                                 unsigned* __restrict__ dub,
                                                 int M) {
    __shared__ float sdtc[32][32];
    __shared__ float swdt[32][256];
    int tid = threadIdx.x;
    int e0 = (blockIdx.x & 3) * 256;
    int m0 = (blockIdx.x >> 2) * 32;
#pragma unroll
    for (int i = 0; i < 4; i++) {
        int idx = tid + 256 * i;
        int m = idx >> 5, r = idx & 31;
        float v = 0.f;
#pragma unroll
        for (int ks = 0; ks < KS64; ks++) v += part[((size_t)ks * M + m0 + m) * 64 + r];
        sdtc[m][r] = v;
    }
#pragma unroll
    for (int r = 0; r < 32; r++) swdt[r][tid] = Wdt[(size_t)r * DI + e0 + tid];
    __syncthreads();
    float wc[32];
#pragma unroll
    for (int r = 0; r < 32; r++) wc[r] = swdt[r][tid];
    float bv = bdt[e0 + tid];
    for (int m = 0; m < 32; m++) {
        float acc = bv;
#pragma unroll
        for (int r4 = 0; r4 < 8; r4++) {
            float4 d4 = *(const float4*)&sdtc[m][r4 * 4];
            acc = fmaf(d4.x, wc[r4 * 4 + 0], acc);
            acc = fmaf(d4.y, wc[r4 * 4 + 1], acc);
            acc = fmaf(d4.z, wc[r4 * 4 + 2], acc);
            acc = fmaf(d4.w, wc[r4 * 4 + 3], acc);
        }
        float sp = (acc > 20.f) ? acc : log1pf(__expf(acc));
        unsigned dt16 = (unsigned)__bfloat16_as_ushort(__float2bfloat16(sp));
        unsigned u16  = (unsigned)ucb[(size_t)(m0 + m) * DI + e0 + tid];
        dub[(size_t)(m0 + m) * DI + e0 + tid] = (dt16 << 16) | u16;
    }
}

// ---------------- scan v9: 2 LDS reads/t (packed du + packed BC), global z/sq ----------------
__device__ __forceinline__ void scan_stage(unsigned* sDU, unsigned* sBC,
                                           const unsigned* __restrict__ dub_row,
                                           const unsigned* __restrict__ bcb_row,
                                           int e_base, int tid, int tc) {
    int w = tid >> 6;
    int t4 = tid >> 2, c4 = tid & 3;
    gll16(dub_row + (size_t)(tc + t4) * 1024 + e_base + c4 * 4, sDU + w * 256);
    gll16(bcb_row + (size_t)(tc + t4) * 16 + c4 * 4,            sBC + w * 256);
}

__device__ __forceinline__ void scan_flush(const float* yb, __hip_bfloat16* ob,
                                           int e_base, int tcp, int tid) {
#pragma unroll
    for (int r = 0; r < 2; r++) {
        int pid = r * 256 + tid;
        int t = pid >> 3, ep = pid & 7;
        float2 y2 = *(const float2*)&yb[t * YSTR + ep * 2];
        __hip_bfloat162 v;
        v.x = __float2bfloat16(y2.x);
        v.y = __float2bfloat16(y2.y);
        *(__hip_bfloat162*)&ob[(size_t)(tcp + t) * DI + e_base + ep * 2] = v;
    }
}

__global__ __launch_bounds__(256) void scan_kernel(const unsigned* __restrict__ dub,
                                                   const unsigned short* __restrict__ uzb,
                                                   const unsigned* __restrict__ bcb,
                                                   const float* __restrict__ ssqb,
                                                   const float* __restrict__ Alog,
                                                   const float* __restrict__ Dv,
                                                   __hip_bfloat16* __restrict__ out) {
    __shared__ __align__(16) unsigned sDU[2][CH * 16];
    __shared__ __align__(16) unsigned sBC[2][CH * 16];
    __shared__ __align__(16) float    yb [2][CH * YSTR];
    int tid = threadIdx.x;
    int g = tid >> 4, n = tid & 15;
    int b = blockIdx.x >> 6;
    int e_base = (blockIdx.x & 63) << 4;
    int e = e_base + g;
    float An2 = -__expf(Alog[e * DST + n]) * 1.4426950408889634f;
    float dv = Dv[e];
    const unsigned*       dub_row = dub + (size_t)b * SEQL * DI;
    const unsigned short* uzb_row = uzb + (size_t)b * SEQL * 2048;
    const unsigned*       bcb_row = bcb + (size_t)b * SEQL * 16;
    const float*          sqb     = ssqb + (size_t)b * SEQL;
    __hip_bfloat16* ob = out + (size_t)b * SEQL * DI;
    float h = 0.f;
    scan_stage(sDU[0], sBC[0], dub_row, bcb_row, e_base, tid, 0);
    int buf = 0;
    for (int c = 0; c < SEQL / CH; c++) {
        int tc = c * CH;
        __syncthreads();
        if (c + 1 < SEQL / CH)
            scan_stage(sDU[buf ^ 1], sBC[buf ^ 1], dub_row, bcb_row, e_base, tid, tc + CH);
        if (c > 0)
            scan_flush(yb[buf ^ 1], ob, e_base, tc - CH, tid);
        const unsigned* pDU = sDU[buf];
        const unsigned* pBC = sBC[buf];
        float* pY = yb[buf];
        for (int ts = 0; ts < CH; ts += 16) {
            int tl = ts + n;
            // off-chain global reads for the epilogue (L2-resident, hoisted by scheduler)
            float sq = sqb[tc + tl];
            float zv = bf2f(uzb_row[(size_t)(tc + tl) * 2048 + 1024 + e]);
            float pc = 0.f, ucap = 0.f;
#pragma unroll
            for (int j = 0; j < 16; j++) {
                int t = ts + j;
                unsigned du = pDU[t * 16 + g];
                float dtv = __uint_as_float(du & 0xFFFF0000u);
                float uv  = __uint_as_float(du << 16);
                unsigned bcd = pBC[t * 16 + n];
                float Bn = __uint_as_float(bcd << 16);
                float Cn = __uint_as_float(bcd & 0xFFFF0000u);
                float a = __builtin_amdgcn_exp2f(dtv * An2);
                h = fmaf(a, h, dtv * uv * Bn);
                float p = sum16(h * Cn);
                h = fmaf(uv - p, ALPHA_C * Cn, h);
                bool cap = (n == j);
                pc   = cap ? p  : pc;
                ucap = cap ? uv : ucap;
            }
            float es2 = ALPHA_C * (ucap - pc);
            float y = fmaf(dv, ucap, fmaf(es2, sq, pc));
            float sz = zv / (1.f + __expf(-zv));
            pY[tl * YSTR + g] = y * sz;
        }
        buf ^= 1;
    }
    __syncthreads();
    scan_flush(yb[buf ^ 1], ob, e_base, SEQL - CH, tid);
}

// ---------------- mean-pool partials ----------------
__global__ __launch_bounds__(512) void pool_kernel(const float* __restrict__ t,
                                                   float* __restrict__ part) {
    int b = blockIdx.x >> 4;
    int c = blockIdx.x & 15;
    int d = threadIdx.x;
    const float* tb = t + ((size_t)b * SEQL + c * 64) * DM + d;
    float s = 0.f;
    for (int l = 0; l < 64; l++) s += tb[(size_t)l * DM];
    part[(size_t)blockIdx.x * DM + d] = s;
}

// ---------------- final: mean, layernorm, classifier ----------------
__global__ __launch_bounds__(512) void final_kernel(const float* __restrict__ part,
                                                    const float* __restrict__ lw,
                                                    const float* __restrict__ lb,
                                                    const float* __restrict__ Wc,
                                                    const float* __restrict__ bc,
                                                    float* __restrict__ out) {
    int b = blockIdx.x;
    int d = threadIdx.x;
    float v = 0.f;
    for (int c = 0; c < 16; c++) v += part[((size_t)b * 16 + c) * DM + d];
    v *= (1.f / SEQL);
    __shared__ float sh[512], sh2[512], nd[512];
    sh[d] = v; sh2[d] = v * v;
    __syncthreads();
    for (int off = 256; off > 0; off >>= 1) {
        if (d < off) { sh[d] += sh[d + off]; sh2[d] += sh2[d + off]; }
        __syncthreads();
    }
    float mu  = sh[0]  * (1.f / DM);
    float var = sh2[0] * (1.f / DM) - mu * mu;
    float rs  = rsqrtf(var + LNEPS);
    nd[d] = (v - mu) * rs * lw[d] + lb[d];
    __syncthreads();
    if (d < 10) {
        float acc = bc[d];
        for (int k = 0; k < DM; k++) acc += nd[k] * Wc[k * 10 + d];
        out[b * 10 + d] = acc;
    }
}

extern "C" void kernel_launch(void* const* d_in, const int* in_sizes, int n_in,
                              void* d_out, int out_size, void* d_ws, size_t ws_size,
                              hipStream_t stream) {
    const float* x      = (const float*)d_in[0];
    const float* W_inp  = (const float*)d_in[1];
    const float* b_inp  = (const float*)d_in[2];
    const float* W_in   = (const float*)d_in[3];
    const float* b_in   = (const float*)d_in[4];
    const float* conv_w = (const float*)d_in[5];
    const float* conv_b = (const float*)d_in[6];
    const float* W_x    = (const float*)d_in[7];
    const float* W_dt   = (const float*)d_in[8];
    const float* b_dt   = (const float*)d_in[9];
    const float* A_log  = (const float*)d_in[10];
    const float* D_skip = (const float*)d_in[11];
    const float* W_out  = (const float*)d_in[12];
    const float* b_out  = (const float*)d_in[13];
    const float* ln_w   = (const float*)d_in[14];
    const float* ln_b   = (const float*)d_in[15];
    const float* lnf_w  = (const float*)d_in[16];
    const float* lnf_b  = (const float*)d_in[17];
    const float* W_cls  = (const float*)d_in[18];
    const float* b_cls  = (const float*)d_in[19];

    const int M = BSZ * SEQL;   // 8192

    float* ws = (float*)d_ws;
    float* t_buf = ws;                          ws += (size_t)M * DM;
    unsigned short* uzb = (unsigned short*)ws;  ws += (size_t)M * 2048 / 2;
    unsigned short* ucb = (unsigned short*)ws;  ws += (size_t)M * DI / 2;
    unsigned* dub  = (unsigned*)ws;             ws += (size_t)M * DI;
    unsigned* bcbu = (unsigned*)ws;             ws += (size_t)M * 16;
    float* ssqb  = ws;                          ws += (size_t)M;
    unsigned short* xn_bf = (unsigned short*)ws;  ws += (size_t)M * DM / 2;
    unsigned short* ucs_bf = (unsigned short*)ws; ws += (size_t)M * DI / 2;
    float* partb = ws;                          ws += (size_t)KS64 * M * 64;
    unsigned short* wtin_bf  = (unsigned short*)ws; ws += (size_t)NLAYERS * DM * 2048 / 2;
    unsigned short* wtout_bf = (unsigned short*)ws; ws += (size_t)NLAYERS * DI * DM / 2;
    unsigned short* wxt_bf   = (unsigned short*)ws; ws += (size_t)NLAYERS * DI * 64 / 2 + 64;
    float* poolp = ws;                          ws += (size_t)128 * DM;

    embed_kernel<<<(M * DM + 255) / 256, 256, 0, stream>>>(x, W_inp, b_inp, t_buf);
    transpose_bf_kernel<<<dim3(DM / 32, 2048 / 32, NLAYERS), 256, 0, stream>>>(
        W_in, (__hip_bfloat16*)wtin_bf, DM, 2048, (size_t)DM * 2048);
    transpose_bf_kernel<<<dim3(DI / 32, DM / 32, NLAYERS), 256, 0, stream>>>(
        W_out, (__hip_bfloat16*)wtout_bf, DI, DM, (size_t)DI * DM);
    transpose_bf_kernel<<<dim3(DI / 32, 64 / 32, NLAYERS), 256, 0, stream>>>(
        W_x, (__hip_bfloat16*)wxt_bf, DI, 64, (size_t)DI * 64);

    for (int i = 0; i < NLAYERS; i++) {
        ln_kernel<<<M, 256, 0, stream>>>(t_buf, ln_w + i * DM, ln_b + i * DM,
                                         (__hip_bfloat16*)xn_bf);
        gemm_mfma_kernel<2><<<dim3(M / 128, 2048 / 128), 256, 0, stream>>>(
            (const short*)xn_bf, (const short*)(wtin_bf + (size_t)i * DM * 2048),
            b_in + i * 2048, uzb, M, 2048, DM);
        conv_kernel<<<(M * DI) / 256, 256, 0, stream>>>(
            uzb, conv_w + (size_t)i * DI * 4, conv_b + i * DI, ucb);
        gemm64_mfma_kernel<<<dim3(M / 128, KS64), 256, 0, stream>>>(
            (const short*)ucb, (const short*)(wxt_bf + (size_t)i * DI * 64), partb, M);
        repack_kernel<<<M / 8, 256, 0, stream>>>(partb, bcbu, ssqb, M);
        dt_kernel<<<(M / 32) * 4, 256, 0, stream>>>(
            partb, W_dt + (size_t)i * DTR * DI, b_dt + i * DI, ucb, dub, M);
        scan_kernel<<<BSZ * DI / 16, 256, 0, stream>>>(
            dub, uzb, bcbu, ssqb, A_log + (size_t)i * DI * DST, D_skip + i * DI,
            (__hip_bfloat16*)ucs_bf);
        gemm6464_res_kernel<<<dim3(M / 64, DM / 64), 256, 0, stream>>>(
            (const short*)ucs_bf, (const short*)(wtout_bf + (size_t)i * DI * DM),
            b_out + i * DM, t_buf, M, DM, DI);
    }

    pool_kernel<<<128, 512, 0, stream>>>(t_buf, poolp);
    final_kernel<<<8, 512, 0, stream>>>(poolp, lnf_w, lnf_b, W_cls, b_cls, (float*)d_out);
}